// Round 6
// baseline (31770.544 us; speedup 1.0000x reference)
//
#include <hip/hip_runtime.h>
#include <hip/hip_bf16.h>

// Problem constants
#define NSEQ 320     // 256 tran sub-seqs + 32 doc_anchor + 32 doc_neg
#define NTRAN 256
#define TT 128       // tran T
#define TDOC 256     // doc T
#define EH 512       // E == H == 512

#define WT_SZ (1024*2048)            // wT: [k][row], k-major
#define AWT_SZ (512*512)             // awT: [k][j]
#define SC_W 258
#define XROWS_TRAN (256*TT)          // 32768
#define XROWS (XROWS_TRAN + 64*TDOC) // 49152

// ---- module-global scratch ----
__device__ float g_wT[2*WT_SZ];      // [tran|doc][k][row]
__device__ float g_awT[2*AWT_SZ];    // [tran|doc][k][j]
__device__ float g_x[(size_t)XROWS*EH]; // pre-gathered embeddings [row][512] (~100 MB)
__device__ float g_h[3*NSEQ*EH];     // h ring buffer [slot][seq][j]
__device__ float g_c[NSEQ*EH];
__device__ float g_acc[NSEQ*EH];     // online-softmax numerator
__device__ float g_ml[64*NSEQ*2];    // per-(j_tile,seq) {m,l}; doc uses 64 jt
__device__ float g_sc[NSEQ*SC_W];    // attention scores
__device__ float g_pool[NSEQ*EH];
__device__ float g_loss;

__device__ __forceinline__ float sigm(float x) { return 1.0f / (1.0f + expf(-x)); }

__device__ __forceinline__ int seq_len(int s, const int* __restrict__ tbl,
                                       const int* __restrict__ dal, const int* __restrict__ dnl) {
  if (s < NTRAN) return tbl[s];
  if (s < NTRAN+32) return dal[s-NTRAN];
  return dnl[s-NTRAN-32];
}

// ---------------- init state each call ----------------
__global__ __launch_bounds__(256) void init_state() {
  int i = blockIdx.x*256 + threadIdx.x;
  if (i < 3*NSEQ*EH) g_h[i] = 0.0f;
  if (i < NSEQ*EH)  { g_c[i] = 0.0f; g_acc[i] = 0.0f; }
  if (i < NSEQ*SC_W) g_sc[i] = 0.0f;
  if (i < 64*NSEQ*2) g_ml[i] = (i & 1) ? 0.0f : -3.0e38f;
  if (i == 0) g_loss = 0.0f;
}

// ---------------- build transposed weights ----------------
__global__ __launch_bounds__(256) void build_wt(
    const float* __restrict__ wih_t, const float* __restrict__ whh_t,
    const float* __restrict__ wih_d, const float* __restrict__ whh_d,
    const float* __restrict__ aw_t,  const float* __restrict__ aw_d) {
  int idx = blockIdx.x*256 + threadIdx.x;
  const int NW = WT_SZ;
  if (idx < 2*NW) {
    int p = idx / NW; int r2 = idx % NW;
    int k = r2 / 2048; int r = r2 % 2048;
    const float* wih = p ? wih_d : wih_t;
    const float* whh = p ? whh_d : whh_t;
    float v = (k < 512) ? wih[r*512 + k] : whh[r*512 + (k - 512)];
    g_wT[p*NW + k*2048 + r] = v;
  } else {
    idx -= 2*NW;
    if (idx < 2*AWT_SZ) {
      int p = idx / AWT_SZ; int q = idx % AWT_SZ;
      int k = q / 512; int j = q % 512;
      const float* aw = p ? aw_d : aw_t;
      g_awT[p*AWT_SZ + k*512 + j] = aw[j*512 + k];
    }
  }
}

// ---------------- pre-gather all embeddings: g_x[row][512] ----------------
// row < 32768: tran seq s=row/128, t=row%128 (tran is flat [256][128]).
// else: doc rows, da first (8192) then dn (8192).
__global__ __launch_bounds__(128) void pregather(
    const int* __restrict__ tran, const int* __restrict__ da_tok,
    const int* __restrict__ dn_tok, const float* __restrict__ emb) {
  int row = blockIdx.x;
  int tok;
  if (row < XROWS_TRAN) tok = tran[row];
  else {
    int q = row - XROWS_TRAN;
    tok = (q < 32*TDOC) ? da_tok[q] : dn_tok[q - 32*TDOC];
  }
  const float4* src = (const float4*)&emb[(size_t)tok*EH];
  float4* dst = (float4*)&g_x[(size_t)row*EH];
  dst[threadIdx.x] = src[threadIdx.x];
}

// ---------------- per-timestep fused kernel ----------------
// t<=129: 512 blocks = 256 tran (16nt x 16jt, JW=32) + 256 doc (4nt x 64jt, JW=8)
//         => 2 blocks/CU balanced; per SIMD 1 tran wave + 1 doc wave.
// t>=130: 256 doc blocks only.
// jt%8 == blockIdx%8 => weight slices pinned per-XCD => L2-resident (~2MB/XCD).
// Operands (x from g_x, h from g_h) are read with wave-uniform addresses (scalarizable);
// LDS is only a 16KB reduce buffer.
// Phase A: score partials for h_{t-1} -> atomicAdd g_sc (finalized at kernel boundary)
// Phase B: online-softmax acc update for h_{t-2}
// Phase C: gates (k-split across threads, LDS-reduced) + c/h update
__global__ __launch_bounds__(256) void step_kernel(
    int t, int tran_present,
    const int* __restrict__ tbl, const int* __restrict__ dal, const int* __restrict__ dnl,
    const float* __restrict__ b_tran,  const float* __restrict__ b_doc,
    const float* __restrict__ ab_tran, const float* __restrict__ ab_doc,
    const float* __restrict__ sw_tran, const float* __restrict__ sw_doc,
    const float* __restrict__ sb_tran, const float* __restrict__ sb_doc) {
  __shared__ float red[4096];          // 16KB: [tid][16] partials
  const int tid = threadIdx.x;
  const int idx = blockIdx.x;

  bool isdoc; int nt, jt, lgJW;
  if (tran_present && idx < 256) { nt = idx >> 4; jt = idx & 15; isdoc = false; lgJW = 5; }
  else {
    int q = tran_present ? (idx - 256) : idx;
    nt = 16 + (q >> 6); jt = q & 63; isdoc = true; lgJW = 3;
  }
  const int JW    = 1 << lgJW;         // h-cols per block: 32 / 8
  const int lgCPB = lgJW + 2;
  const int CPB   = 1 << lgCPB;        // gate cols: 128 / 32
  const int ksC   = 256 >> lgCPB;      // k-split C: 2 / 8
  const int kcntC = CPB << 2;          // k per split: 512 / 128
  const int ksA   = 256 >> lgJW;       // k-split A: 8 / 32
  const int kcntA = JW << 1;           // k per split: 64 / 16

  const int sbase = nt * 16;
  const int Ts = isdoc ? TDOC : TT;

  const float* __restrict__ wT   = g_wT  + (isdoc ? WT_SZ  : 0);
  const float* __restrict__ awT  = g_awT + (isdoc ? AWT_SZ : 0);
  const float* __restrict__ bias = isdoc ? b_doc   : b_tran;
  const float* __restrict__ ab   = isdoc ? ab_doc  : ab_tran;
  const float* __restrict__ sw   = isdoc ? sw_doc  : sw_tran;
  const float  sb = isdoc ? sb_doc[0] : sb_tran[0];

  const int hp = (t + 2) % 3;   // h_{t-1}
  const int hc = t % 3;         // h_t (written)
  const int h2 = (t + 1) % 3;   // h_{t-2}

  const bool doA = (t >= 1) && ((t - 1) < Ts);
  const bool doC = (t < Ts);

  // ---- Phase A partials: u[n][col] = sum_k h[n][k] * aw[col][k] ----
  if (doA) {
    const int jl  = tid & (JW - 1);
    const int ksI = tid >> lgJW;
    const int col = (jt << lgJW) + jl;
    const int k0  = ksI * kcntA;
    float ua[16];
    #pragma unroll
    for (int n = 0; n < 16; ++n) ua[n] = 0.0f;
    const float* __restrict__ hB = &g_h[(hp*NSEQ + sbase)*EH];
    for (int kq = 0; kq < kcntA; kq += 4) {
      const int kp = k0 + kq;
      const float a0 = awT[(kp+0)*512 + col];
      const float a1 = awT[(kp+1)*512 + col];
      const float a2 = awT[(kp+2)*512 + col];
      const float a3 = awT[(kp+3)*512 + col];
      #pragma unroll
      for (int n = 0; n < 16; ++n) {
        float4 xv = *(const float4*)&hB[n*EH + kp];   // wave-uniform addr
        ua[n] = fmaf(a0, xv.x, ua[n]); ua[n] = fmaf(a1, xv.y, ua[n]);
        ua[n] = fmaf(a2, xv.z, ua[n]); ua[n] = fmaf(a3, xv.w, ua[n]);
      }
    }
    #pragma unroll
    for (int n = 0; n < 16; ++n) red[(tid << 4) + n] = ua[n];
  }
  __syncthreads();

  // ---- Phase A finish: k-reduce, tanh*sw, j-reduce (shuffle), atomicAdd ----
  if (doA) {
    for (int i2 = tid; i2 < (16 << lgJW); i2 += 256) {
      const int jl = i2 & (JW - 1);
      const int n  = i2 >> lgJW;
      const int jg = (jt << lgJW) + jl;
      float u = ab[jg];
      for (int ksI = 0; ksI < ksA; ++ksI)
        u += red[((((ksI << lgJW) + jl)) << 4) + n];
      float p = tanhf(u) * sw[jg];
      for (int off = JW >> 1; off >= 1; off >>= 1) p += __shfl_xor(p, off, 64);
      if (jl == 0) {
        float extra = (jt == 0) ? sb : 0.0f;
        atomicAdd(&g_sc[(sbase + n)*SC_W + (t - 1)], p + extra);
      }
    }
  }

  // ---- Phase B: online-softmax accumulate h_{t-2} ----
  if (t >= 2) {
    for (int i2 = tid; i2 < (16 << lgJW); i2 += 256) {
      const int jl = i2 & (JW - 1);
      const int n  = i2 >> lgJW;
      const int s  = sbase + n;
      const int len = seq_len(s, tbl, dal, dnl);
      if ((t - 2) < len) {
        float sval = g_sc[s*SC_W + (t - 2)];
        float* mlp = &g_ml[(jt*NSEQ + s)*2];
        float m_old = mlp[0], l_old = mlp[1];
        float m_new = fmaxf(m_old, sval);
        float alpha = expf(m_old - m_new);
        float e = expf(sval - m_new);
        const int jg = (jt << lgJW) + jl;
        float hv = g_h[(h2*NSEQ + s)*EH + jg];
        g_acc[s*EH + jg] = g_acc[s*EH + jg]*alpha + e*hv;
        if (jl == 0) { mlp[0] = m_new; mlp[1] = l_old*alpha + e; }
      }
    }
  }
  __syncthreads();   // red free for Phase C

  // ---- Phase C partials: gates[n][col] = sum_k xh[n][k] * w[col][k] ----
  if (doC) {
    const int r    = tid & (CPB - 1);
    const int kg   = tid >> lgCPB;
    const int gate = r >> lgJW;
    const int jcol = r & (JW - 1);
    const int col  = (gate << 9) + (jt << lgJW) + jcol;
    const int kstart = kg * kcntC;
    const bool isx = (kstart < 512);     // k-split halves never straddle x|h boundary
    float acc[16];
    #pragma unroll
    for (int n = 0; n < 16; ++n) acc[n] = 0.0f;
    const float* __restrict__ wp = wT + col;
    for (int k = kstart; k < kstart + kcntC; k += 4) {
      const float w0 = wp[(k+0)*2048];
      const float w1 = wp[(k+1)*2048];
      const float w2 = wp[(k+2)*2048];
      const float w3 = wp[(k+3)*2048];
      #pragma unroll
      for (int n = 0; n < 16; ++n) {
        const int s = sbase + n;
        const float* __restrict__ src = isx
          ? &g_x[(size_t)(isdoc ? XROWS_TRAN + (s - NTRAN)*TDOC + t : s*TT + t)*EH + k]
          : &g_h[(hp*NSEQ + s)*EH + (k - 512)];
        float4 xv = *(const float4*)src;                // wave-uniform addr
        acc[n] = fmaf(w0, xv.x, acc[n]); acc[n] = fmaf(w1, xv.y, acc[n]);
        acc[n] = fmaf(w2, xv.z, acc[n]); acc[n] = fmaf(w3, xv.w, acc[n]);
      }
    }
    #pragma unroll
    for (int n = 0; n < 16; ++n) red[(tid << 4) + n] = acc[n];
  }
  __syncthreads();

  // ---- Phase C reduce: sum k-splits + bias (slot-owner in-place, race-free) ----
  if (doC) {
    for (int i2 = tid; i2 < (CPB << 4); i2 += 256) {
      const int r = i2 >> 4; const int n = i2 & 15;
      const int gate = r >> lgJW; const int jcol = r & (JW - 1);
      const int row = (gate << 9) + (jt << lgJW) + jcol;
      float v = bias[row];
      for (int kg = 0; kg < ksC; ++kg) v += red[((kg*CPB + r) << 4) + n];
      red[(r << 4) + n] = v;
    }
  }
  __syncthreads();

  // ---- c/h update ----
  if (doC) {
    for (int i2 = tid; i2 < (16 << lgJW); i2 += 256) {
      const int jl = i2 & (JW - 1);
      const int n  = i2 >> lgJW;
      const int s  = sbase + n;
      const float gi = red[((0*JW + jl) << 4) + n];
      const float gf = red[((1*JW + jl) << 4) + n];
      const float gg = red[((2*JW + jl) << 4) + n];
      const float go = red[((3*JW + jl) << 4) + n];
      const int jg = (jt << lgJW) + jl;
      float cv = g_c[s*EH + jg];
      float cn = sigm(gf)*cv + sigm(gi)*tanhf(gg);
      float hn = sigm(go)*tanhf(cn);
      g_c[s*EH + jg] = cn;
      g_h[(hc*NSEQ + s)*EH + jg] = hn;
    }
  }
}

// ---------------- finalize pooled = acc / l  (tanh on tran path) ----------------
__global__ __launch_bounds__(256) void finalize_pool() {
  int s = blockIdx.x;
  float l = g_ml[s*2 + 1];   // jt 0 copy
  for (int j = threadIdx.x; j < EH; j += 256) {
    float v = g_acc[s*EH + j] / l;
    if (s < NTRAN) v = tanhf(v);
    g_pool[s*EH + j] = v;
  }
}

// ---------------- per-batch cosine terms + loss accumulate ----------------
__global__ __launch_bounds__(256) void loss_partial() {
  __shared__ float red[5][4];
  int b = blockIdx.x, tid = threadIdx.x;
  float p[5] = {0.f, 0.f, 0.f, 0.f, 0.f};
  for (int j = tid; j < EH; j += 256) {
    float m = -3.0e38f;
    #pragma unroll
    for (int bl = 0; bl < 8; bl++) m = fmaxf(m, g_pool[(b*8 + bl)*EH + j]);
    float da = g_pool[(NTRAN + b)*EH + j];
    float dn = g_pool[(NTRAN + 32 + b)*EH + j];
    p[0] += m*m; p[1] += da*da; p[2] += dn*dn; p[3] += m*da; p[4] += m*dn;
  }
  int lane = tid & 63, w = tid >> 6;
  #pragma unroll
  for (int i = 0; i < 5; i++) {
    float v = p[i];
    for (int off = 32; off >= 1; off >>= 1) v += __shfl_xor(v, off, 64);
    if (lane == 0) red[i][w] = v;
  }
  __syncthreads();
  if (tid == 0) {
    float cc = red[0][0] + red[0][1] + red[0][2] + red[0][3];
    float aa = red[1][0] + red[1][1] + red[1][2] + red[1][3];
    float nn = red[2][0] + red[2][1] + red[2][2] + red[2][3];
    float ca = red[3][0] + red[3][1] + red[3][2] + red[3][3];
    float cn = red[4][0] + red[4][1] + red[4][2] + red[4][3];
    float ncr = fmaxf(sqrtf(cc), 1e-8f);
    float nda = fmaxf(sqrtf(aa), 1e-8f);
    float ndn = fmaxf(sqrtf(nn), 1e-8f);
    float simA = ca / (ncr * nda);
    float simN = cn / (ncr * ndn);
    float term = fmaxf(0.05f - simA + simN, 1e-6f);
    atomicAdd(&g_loss, term * (1.0f / 32.0f));
  }
}

__global__ void write_out(float* __restrict__ out) {
  if (threadIdx.x == 0 && blockIdx.x == 0) out[0] = g_loss;
}

extern "C" void kernel_launch(void* const* d_in, const int* in_sizes, int n_in,
                              void* d_out, int out_size, void* d_ws, size_t ws_size,
                              hipStream_t stream) {
  (void)in_sizes; (void)n_in; (void)out_size; (void)d_ws; (void)ws_size;
  const int*   tran   = (const int*)d_in[0];
  const int*   tbl    = (const int*)d_in[2];   // tran_block_len (tran_len unused by ref)
  const int*   da_tok = (const int*)d_in[3];
  const int*   dal    = (const int*)d_in[4];
  const int*   dn_tok = (const int*)d_in[5];
  const int*   dnl    = (const int*)d_in[6];
  const float* emb    = (const float*)d_in[7];
  const float* wih_t  = (const float*)d_in[8];
  const float* whh_t  = (const float*)d_in[9];
  const float* b_t    = (const float*)d_in[10];
  const float* wih_d  = (const float*)d_in[11];
  const float* whh_d  = (const float*)d_in[12];
  const float* b_d    = (const float*)d_in[13];
  const float* aw_t   = (const float*)d_in[14];
  const float* ab_t   = (const float*)d_in[15];
  const float* sw_t   = (const float*)d_in[16];
  const float* sb_t   = (const float*)d_in[17];
  const float* aw_d   = (const float*)d_in[18];
  const float* ab_d   = (const float*)d_in[19];
  const float* sw_d   = (const float*)d_in[20];
  const float* sb_d   = (const float*)d_in[21];

  init_state<<<(3*NSEQ*EH + 255) / 256, 256, 0, stream>>>();
  build_wt<<<(2*WT_SZ + 2*AWT_SZ + 255) / 256, 256, 0, stream>>>(
      wih_t, whh_t, wih_d, whh_d, aw_t, aw_d);
  pregather<<<XROWS, 128, 0, stream>>>(tran, da_tok, dn_tok, emb);

  for (int t = 0; t <= 257; ++t) {
    int present = (t <= 129) ? 1 : 0;
    int nb = present ? 512 : 256;
    step_kernel<<<nb, 256, 0, stream>>>(
        t, present, tbl, dal, dnl,
        b_t, b_d, ab_t, ab_d, sw_t, sw_d, sb_t, sb_d);
  }

  finalize_pool<<<NSEQ, 256, 0, stream>>>();
  loss_partial<<<32, 256, 0, stream>>>();
  write_out<<<1, 64, 0, stream>>>((float*)d_out);
}

// Round 7
// 13357.956 us; speedup vs baseline: 2.3784x; 2.3784x over previous
//
#include <hip/hip_runtime.h>
#include <hip/hip_bf16.h>

// Problem constants
#define NSEQ 320
#define NTRAN 256
#define TT 128
#define TDOC 256
#define EH 512
#define NG 2048
#define WT_SZ (1024*2048)            // wT: [k][row], k-major (k<512: wih, k>=512: whh)
#define AWT_SZ (512*512)             // awT: [k][j]
#define SC_W 258
#define XR_TRAN (NTRAN*TT)           // 32768
#define XROWS (XR_TRAN + 64*TDOC)    // 49152

// ---- module-global scratch ----
__device__ float g_wT[2*WT_SZ];          // [tran|doc][k][row]
__device__ float g_awT[2*AWT_SZ];        // [tran|doc][k][j]
__device__ float g_x [(size_t)XROWS*EH]; // gathered embeddings (~100MB)
__device__ float g_xp[(size_t)XROWS*NG]; // hoisted xproj + bias (~402MB)
__device__ float g_h [3*NSEQ*EH];        // h ring [slot][seq][j]
__device__ float g_hT[3*EH*NSEQ];        // h ring transposed [slot][j][seq]
__device__ float g_c [NSEQ*EH];
__device__ float g_acc[NSEQ*EH];
__device__ float g_ml[4*NSEQ*2];         // per-(ct,seq) {m,l}
__device__ float g_sc[NSEQ*SC_W];
__device__ float g_pool[NSEQ*EH];
__device__ float g_loss;

__device__ __forceinline__ float sigm(float x) { return 1.0f / (1.0f + expf(-x)); }

__device__ __forceinline__ int seq_len(int s, const int* __restrict__ tbl,
                                       const int* __restrict__ dal, const int* __restrict__ dnl) {
  if (s < NTRAN) return tbl[s];
  if (s < NTRAN+32) return dal[s-NTRAN];
  return dnl[s-NTRAN-32];
}

// ---------------- init state each call ----------------
__global__ __launch_bounds__(256) void init_state() {
  int i = blockIdx.x*256 + threadIdx.x;
  if (i < 3*NSEQ*EH) { g_h[i] = 0.0f; g_hT[i] = 0.0f; }
  if (i < NSEQ*EH)  { g_c[i] = 0.0f; g_acc[i] = 0.0f; }
  if (i < NSEQ*SC_W) g_sc[i] = 0.0f;
  if (i < 4*NSEQ*2)  g_ml[i] = (i & 1) ? 0.0f : -3.0e38f;
  if (i == 0) g_loss = 0.0f;
}

// ---------------- build transposed weights ----------------
__global__ __launch_bounds__(256) void build_wt(
    const float* __restrict__ wih_t, const float* __restrict__ whh_t,
    const float* __restrict__ wih_d, const float* __restrict__ whh_d,
    const float* __restrict__ aw_t,  const float* __restrict__ aw_d) {
  int idx = blockIdx.x*256 + threadIdx.x;
  const int NW = WT_SZ;
  if (idx < 2*NW) {
    int p = idx / NW; int r2 = idx % NW;
    int k = r2 / 2048; int r = r2 % 2048;
    const float* wih = p ? wih_d : wih_t;
    const float* whh = p ? whh_d : whh_t;
    float v = (k < 512) ? wih[r*512 + k] : whh[r*512 + (k - 512)];
    g_wT[p*NW + k*2048 + r] = v;
  } else {
    idx -= 2*NW;
    if (idx < 2*AWT_SZ) {
      int p = idx / AWT_SZ; int q = idx % AWT_SZ;
      int k = q / 512; int j = q % 512;
      const float* aw = p ? aw_d : aw_t;
      g_awT[p*AWT_SZ + k*512 + j] = aw[j*512 + k];
    }
  }
}

// ---------------- pre-gather embeddings ----------------
__global__ __launch_bounds__(128) void pregather(
    const int* __restrict__ tran, const int* __restrict__ da_tok,
    const int* __restrict__ dn_tok, const float* __restrict__ emb) {
  int row = blockIdx.x;
  int tok;
  if (row < XR_TRAN) tok = tran[row];
  else {
    int q = row - XR_TRAN;
    tok = (q < 32*TDOC) ? da_tok[q] : dn_tok[q - 32*TDOC];
  }
  const float4* src = (const float4*)&emb[(size_t)tok*EH];
  float4* dst = (float4*)&g_x[(size_t)row*EH];
  dst[threadIdx.x] = src[threadIdx.x];
}

// ---------------- hoisted xproj GEMM: g_xp = g_x @ wih^T + b ----------------
// M=49152, N=2048, K=512. 128x128 tiles, 8x8/thread, LDS double-buffer.
__global__ __launch_bounds__(256) void xproj_gemm(
    const float* __restrict__ b_t, const float* __restrict__ b_d) {
  __shared__ float As[2][16][128];
  __shared__ float Bs[2][16][128];
  const int mt = blockIdx.x >> 4, ntb = blockIdx.x & 15;
  const size_t mb = (size_t)mt * 128; const int nb = ntb * 128;
  const bool tp = (mb < XR_TRAN);
  const float* __restrict__ wT = g_wT + (tp ? 0 : WT_SZ);
  const float* __restrict__ bias = tp ? b_t : b_d;
  const int tid = threadIdx.x, tx = tid & 15, ty = tid >> 4;
  float acc[8][8];
  #pragma unroll
  for (int i = 0; i < 8; ++i)
    #pragma unroll
    for (int j = 0; j < 8; ++j) acc[i][j] = 0.0f;

  auto stage = [&](int ks, int buf) {
    const int k0 = ks * 16;
    #pragma unroll
    for (int i = 0; i < 2; ++i) {
      int idx = i*256 + tid; int m = idx & 127, kc = idx >> 7;   // kc 0..3
      float4 v = *(const float4*)&g_x[(mb + m)*512 + k0 + kc*4];
      As[buf][kc*4+0][m] = v.x; As[buf][kc*4+1][m] = v.y;
      As[buf][kc*4+2][m] = v.z; As[buf][kc*4+3][m] = v.w;
    }
    #pragma unroll
    for (int i = 0; i < 2; ++i) {
      int idx = i*256 + tid; int n4 = idx & 31, kk = idx >> 5;   // kk 0..15
      *(float4*)&Bs[buf][kk][n4*4] = *(const float4*)&wT[(size_t)(k0+kk)*2048 + nb + n4*4];
    }
  };
  stage(0, 0); __syncthreads();
  for (int ks = 0; ks < 32; ++ks) {
    const int buf = ks & 1;
    if (ks < 31) stage(ks + 1, buf ^ 1);
    #pragma unroll
    for (int kk = 0; kk < 16; ++kk) {
      float a[8], b[8];
      *(float4*)&a[0] = *(const float4*)&As[buf][kk][ty*8];
      *(float4*)&a[4] = *(const float4*)&As[buf][kk][ty*8+4];
      *(float4*)&b[0] = *(const float4*)&Bs[buf][kk][tx*8];
      *(float4*)&b[4] = *(const float4*)&Bs[buf][kk][tx*8+4];
      #pragma unroll
      for (int i = 0; i < 8; ++i)
        #pragma unroll
        for (int j = 0; j < 8; ++j) acc[i][j] = fmaf(a[i], b[j], acc[i][j]);
    }
    __syncthreads();
  }
  float b8[8];
  #pragma unroll
  for (int j = 0; j < 8; ++j) b8[j] = bias[nb + tx*8 + j];
  #pragma unroll
  for (int i = 0; i < 8; ++i) {
    float* dst = &g_xp[(mb + ty*8 + i)*2048 + nb + tx*8];
    float4 o0 = make_float4(acc[i][0]+b8[0], acc[i][1]+b8[1], acc[i][2]+b8[2], acc[i][3]+b8[3]);
    float4 o1 = make_float4(acc[i][4]+b8[4], acc[i][5]+b8[5], acc[i][6]+b8[6], acc[i][7]+b8[7]);
    *(float4*)dst = o0; *(float4*)(dst+4) = o1;
  }
}

// ---------------- per-timestep fused kernel ----------------
// 512 threads = 8 waves = (k-quarter kq = w>>1) x (n-half nh = w&1).
// Lane owns 8 gate cols (col_local = j*64+lane) x NH seqs. Weights read once/block.
// Operand h staged in ht[k][NPB] padded to 12 (48B rows: b128-aligned, conflict-free).
// Combined grid (t<=129): 160 blocks XCD-pinned:  g&7<4 -> tran ct=g&7 nt=g>>3(0..19);
//   else ct=(g&7)-4, m=g>>3: m<12 tran nt=20+m, else doc nt=m-12.
// Doc-only grid (t>=130): 64 blocks NPB=4: ct=g&3, nt=g>>2.
template<int NPB>
__global__ __launch_bounds__(512) void step_kernel(
    int t, int combined,
    const int* __restrict__ tbl, const int* __restrict__ dal, const int* __restrict__ dnl,
    const float* __restrict__ ab_tran, const float* __restrict__ ab_doc,
    const float* __restrict__ sw_tran, const float* __restrict__ sw_doc,
    const float* __restrict__ sb_tran, const float* __restrict__ sb_doc) {
  constexpr int NH = NPB/2;
  constexpr int lgN = (NPB == 8) ? 3 : 2;
  __shared__ float ht[512*12];        // 24.6KB  [k][n] pad-12
  __shared__ float redC[4*8*64*9];    // 73.7KB  [(kq*8+j)*64+lane]*9 + n
  __shared__ float redA[4*2*64*9];    // 18.4KB  [(kq*2+ja)*64+lane]*9 + n
  __shared__ float gates[512*9];      // 18.4KB  [c_local]*9 + n
  __shared__ float scpart[8];

  const int tid = threadIdx.x;
  const int g = blockIdx.x;
  bool isdoc; int nt, ct;
  if (combined) {
    int x = g & 7, m = g >> 3;
    if (x < 4) { isdoc = false; ct = x; nt = m; }
    else { ct = x - 4; if (m < 12) { isdoc = false; nt = 20 + m; } else { isdoc = true; nt = m - 12; } }
  } else { isdoc = true; ct = g & 3; nt = g >> 2; }
  const int sbase = (isdoc ? NTRAN : 0) + nt * NPB;
  const int Ts = isdoc ? TDOC : TT;

  const float* __restrict__ wT  = g_wT  + (isdoc ? WT_SZ  : 0);
  const float* __restrict__ awT = g_awT + (isdoc ? AWT_SZ : 0);
  const float* __restrict__ ab  = isdoc ? ab_doc : ab_tran;
  const float* __restrict__ sw  = isdoc ? sw_doc : sw_tran;
  const float  sb = isdoc ? sb_doc[0] : sb_tran[0];

  const int hp = (t + 2) % 3, hc = t % 3, h2 = (t + 1) % 3;
  const bool doA = (t >= 1) && ((t - 1) < Ts);
  const bool doC = (t < Ts);

  const int w = tid >> 6, lane = tid & 63;
  const int kq = w >> 1, nh = w & 1;
  const int kbase = kq * 128;

  // ---- stage h_{t-1} into ht[k][n] (from k-major g_hT) ----
  if (doA || doC) {
    for (int i2 = tid; i2 < 512*NPB; i2 += 512) {
      int n = i2 & (NPB-1), k = i2 >> lgN;
      ht[k*12 + n] = g_hT[(hp*EH + k)*NSEQ + sbase + n];
    }
  }
  if (tid < 8) scpart[tid] = 0.0f;
  __syncthreads();

  // ---- Phase A partials (2 attn cols/lane) + Phase C partials (8 gate cols/lane) ----
  if (doA) {
    const int colA0 = ct*128 + lane;
    float ua[2][NH];
    #pragma unroll
    for (int ja = 0; ja < 2; ++ja)
      #pragma unroll
      for (int n = 0; n < NH; ++n) ua[ja][n] = 0.0f;
    #pragma unroll 2
    for (int kk = 0; kk < 128; ++kk) {
      const int k = kbase + kk;
      const float a0 = awT[k*512 + colA0];
      const float a1 = awT[k*512 + colA0 + 64];
      const float* hr = &ht[k*12 + nh*NH];
      #pragma unroll
      for (int n = 0; n < NH; ++n) {
        float hv = hr[n];
        ua[0][n] = fmaf(a0, hv, ua[0][n]);
        ua[1][n] = fmaf(a1, hv, ua[1][n]);
      }
    }
    #pragma unroll
    for (int ja = 0; ja < 2; ++ja)
      #pragma unroll
      for (int n = 0; n < NH; ++n)
        redA[((kq*2 + ja)*64 + lane)*9 + nh*NH + n] = ua[ja][n];
  }
  if (doC) {
    const float* wp[8];
    #pragma unroll
    for (int j = 0; j < 8; ++j) {
      int cl = j*64 + lane;
      int colg = (cl >> 7)*512 + ct*128 + (cl & 127);
      wp[j] = wT + (size_t)(512 + kbase)*2048 + colg;
    }
    float acc[8][NH];
    #pragma unroll
    for (int j = 0; j < 8; ++j)
      #pragma unroll
      for (int n = 0; n < NH; ++n) acc[j][n] = 0.0f;
    #pragma unroll 2
    for (int kk = 0; kk < 128; ++kk) {
      float hv[NH];
      const float* hr = &ht[(kbase + kk)*12 + nh*NH];
      #pragma unroll
      for (int n = 0; n < NH; ++n) hv[n] = hr[n];
      float wv[8];
      #pragma unroll
      for (int j = 0; j < 8; ++j) wv[j] = wp[j][(size_t)kk*2048];
      #pragma unroll
      for (int j = 0; j < 8; ++j)
        #pragma unroll
        for (int n = 0; n < NH; ++n) acc[j][n] = fmaf(wv[j], hv[n], acc[j][n]);
    }
    #pragma unroll
    for (int j = 0; j < 8; ++j)
      #pragma unroll
      for (int n = 0; n < NH; ++n)
        redC[((kq*8 + j)*64 + lane)*9 + nh*NH + n] = acc[j][n];
  }
  __syncthreads();

  // ---- Phase A finalize: k-reduce, tanh*sw, block-partial score -> LDS atomics ----
  if (doA) {
    for (int i2 = tid; i2 < 128*NPB; i2 += 512) {
      int ca = i2 >> lgN, n = i2 & (NPB-1);
      float u = ab[ct*128 + ca];
      #pragma unroll
      for (int q = 0; q < 4; ++q)
        u += redA[((q*2 + (ca >> 6))*64 + (ca & 63))*9 + n];
      float p = tanhf(u) * sw[ct*128 + ca];
      atomicAdd(&scpart[n], p);
    }
  }
  // ---- Phase B: online-softmax accumulate h_{t-2} ----
  if (t >= 2) {
    for (int i2 = tid; i2 < 128*NPB; i2 += 512) {
      int jl = i2 >> lgN, n = i2 & (NPB-1);
      int s = sbase + n;
      int len = seq_len(s, tbl, dal, dnl);
      if ((t - 2) < len) {
        float sval = g_sc[s*SC_W + (t - 2)];
        float* mlp = &g_ml[(ct*NSEQ + s)*2];
        float m_old = mlp[0], l_old = mlp[1];
        float m_new = fmaxf(m_old, sval);
        float alpha = expf(m_old - m_new);
        float e = expf(sval - m_new);
        int jg = ct*128 + jl;
        float hv = g_h[(h2*NSEQ + s)*EH + jg];
        g_acc[s*EH + jg] = g_acc[s*EH + jg]*alpha + e*hv;
        if (jl == 0) { mlp[0] = m_new; mlp[1] = l_old*alpha + e; }
      }
    }
  }
  __syncthreads();

  // ---- score atomic to global; Phase C reduce (+xproj) -> gates ----
  if (doA && tid < NPB) {
    float extra = (ct == 0) ? sb : 0.0f;
    atomicAdd(&g_sc[(sbase + tid)*SC_W + (t - 1)], scpart[tid] + extra);
  }
  if (doC) {
    for (int i2 = tid; i2 < 512*NPB; i2 += 512) {
      int jc = i2 >> lgN, n = i2 & (NPB-1);
      int s = sbase + n;
      float v = 0.0f;
      #pragma unroll
      for (int q = 0; q < 4; ++q)
        v += redC[((q*8 + (jc >> 6))*64 + (jc & 63))*9 + n];
      int colg = (jc >> 7)*512 + ct*128 + (jc & 127);
      size_t row = isdoc ? (size_t)(XR_TRAN + (s - NTRAN)*256 + t) : (size_t)(s*128 + t);
      v += g_xp[row*2048 + colg];
      gates[jc*9 + n] = v;
    }
  }
  __syncthreads();

  // ---- c/h update ----
  if (doC) {
    for (int i2 = tid; i2 < 128*NPB; i2 += 512) {
      int jl = i2 >> lgN, n = i2 & (NPB-1);
      int s = sbase + n;
      float gi = gates[(0*128 + jl)*9 + n];
      float gf = gates[(1*128 + jl)*9 + n];
      float gg = gates[(2*128 + jl)*9 + n];
      float go = gates[(3*128 + jl)*9 + n];
      int jg = ct*128 + jl;
      float cv = g_c[s*EH + jg];
      float cn = sigm(gf)*cv + sigm(gi)*tanhf(gg);
      float hn = sigm(go)*tanhf(cn);
      g_c[s*EH + jg] = cn;
      g_h[(hc*NSEQ + s)*EH + jg] = hn;
      g_hT[(hc*EH + jg)*NSEQ + s] = hn;
    }
  }
}

// ---------------- finalize pooled = acc / l (tanh on tran path) ----------------
__global__ __launch_bounds__(256) void finalize_pool() {
  int s = blockIdx.x;
  float l = g_ml[s*2 + 1];   // ct=0 copy
  for (int j = threadIdx.x; j < EH; j += 256) {
    float v = g_acc[s*EH + j] / l;
    if (s < NTRAN) v = tanhf(v);
    g_pool[s*EH + j] = v;
  }
}

// ---------------- per-batch cosine terms + loss ----------------
__global__ __launch_bounds__(256) void loss_partial() {
  __shared__ float red[5][4];
  int b = blockIdx.x, tid = threadIdx.x;
  float p[5] = {0.f, 0.f, 0.f, 0.f, 0.f};
  for (int j = tid; j < EH; j += 256) {
    float m = -3.0e38f;
    #pragma unroll
    for (int bl = 0; bl < 8; bl++) m = fmaxf(m, g_pool[(b*8 + bl)*EH + j]);
    float da = g_pool[(NTRAN + b)*EH + j];
    float dn = g_pool[(NTRAN + 32 + b)*EH + j];
    p[0] += m*m; p[1] += da*da; p[2] += dn*dn; p[3] += m*da; p[4] += m*dn;
  }
  int lane = tid & 63, w = tid >> 6;
  #pragma unroll
  for (int i = 0; i < 5; i++) {
    float v = p[i];
    for (int off = 32; off >= 1; off >>= 1) v += __shfl_xor(v, off, 64);
    if (lane == 0) red[i][w] = v;
  }
  __syncthreads();
  if (tid == 0) {
    float cc = red[0][0]+red[0][1]+red[0][2]+red[0][3];
    float aa = red[1][0]+red[1][1]+red[1][2]+red[1][3];
    float nn = red[2][0]+red[2][1]+red[2][2]+red[2][3];
    float ca = red[3][0]+red[3][1]+red[3][2]+red[3][3];
    float cn = red[4][0]+red[4][1]+red[4][2]+red[4][3];
    float ncr = fmaxf(sqrtf(cc), 1e-8f);
    float nda = fmaxf(sqrtf(aa), 1e-8f);
    float ndn = fmaxf(sqrtf(nn), 1e-8f);
    float simA = ca / (ncr * nda);
    float simN = cn / (ncr * ndn);
    float term = fmaxf(0.05f - simA + simN, 1e-6f);
    atomicAdd(&g_loss, term * (1.0f / 32.0f));
  }
}

__global__ void write_out(float* __restrict__ out) {
  if (threadIdx.x == 0 && blockIdx.x == 0) out[0] = g_loss;
}

extern "C" void kernel_launch(void* const* d_in, const int* in_sizes, int n_in,
                              void* d_out, int out_size, void* d_ws, size_t ws_size,
                              hipStream_t stream) {
  (void)in_sizes; (void)n_in; (void)out_size; (void)d_ws; (void)ws_size;
  const int*   tran   = (const int*)d_in[0];
  const int*   tbl    = (const int*)d_in[2];
  const int*   da_tok = (const int*)d_in[3];
  const int*   dal    = (const int*)d_in[4];
  const int*   dn_tok = (const int*)d_in[5];
  const int*   dnl    = (const int*)d_in[6];
  const float* emb    = (const float*)d_in[7];
  const float* wih_t  = (const float*)d_in[8];
  const float* whh_t  = (const float*)d_in[9];
  const float* b_t    = (const float*)d_in[10];
  const float* wih_d  = (const float*)d_in[11];
  const float* whh_d  = (const float*)d_in[12];
  const float* b_d    = (const float*)d_in[13];
  const float* aw_t   = (const float*)d_in[14];
  const float* ab_t   = (const float*)d_in[15];
  const float* sw_t   = (const float*)d_in[16];
  const float* sb_t   = (const float*)d_in[17];
  const float* aw_d   = (const float*)d_in[18];
  const float* ab_d   = (const float*)d_in[19];
  const float* sw_d   = (const float*)d_in[20];
  const float* sb_d   = (const float*)d_in[21];

  init_state<<<(3*NSEQ*EH + 255)/256, 256, 0, stream>>>();
  build_wt<<<(2*WT_SZ + 2*AWT_SZ + 255)/256, 256, 0, stream>>>(
      wih_t, whh_t, wih_d, whh_d, aw_t, aw_d);
  pregather<<<XROWS, 128, 0, stream>>>(tran, da_tok, dn_tok, emb);
  xproj_gemm<<<(XROWS/128)*16, 256, 0, stream>>>(b_t, b_d);

  for (int t = 0; t <= 257; ++t) {
    if (t <= 129) {
      step_kernel<8><<<160, 512, 0, stream>>>(t, 1, tbl, dal, dnl,
          ab_t, ab_d, sw_t, sw_d, sb_t, sb_d);
    } else {
      step_kernel<4><<<64, 512, 0, stream>>>(t, 0, tbl, dal, dnl,
          ab_t, ab_d, sw_t, sw_d, sb_t, sb_d);
    }
  }

  finalize_pool<<<NSEQ, 256, 0, stream>>>();
  loss_partial<<<32, 256, 0, stream>>>();
  write_out<<<1, 64, 0, stream>>>((float*)d_out);
}

// Round 8
// 9043.632 us; speedup vs baseline: 3.5130x; 1.4771x over previous
//
#include <hip/hip_runtime.h>
#include <hip/hip_bf16.h>

#define NSEQ 320
#define NTRAN 256
#define TT 128
#define TDOC 256
#define EH 512
#define XR_TRAN (NTRAN*TT)            // 32768
#define XROWS (XR_TRAN + 64*TDOC)     // 49152

// ---- module-global scratch ----
__device__ float g_wT[2*512*2048];        // wih k-major [path][k][row] (xproj only)
__device__ float g_w2T[2*5*512*512];      // recurrence weights [path][cg][k][col]
__device__ float g_x [(size_t)XROWS*EH];  // gathered embeddings
__device__ float g_xp[(size_t)XROWS*2048];// hoisted xproj+bias, gate-interleaved cols
__device__ float g_h [3*NSEQ*EH];         // h ring [slot][seq][dim]
__device__ float g_pool[NSEQ*EH];
__device__ float g_loss;
__device__ unsigned g_cnt[64];            // [ch*32] barrier counters (padded)
__device__ unsigned g_ep[64];             // [ch*32] barrier epochs

__device__ __forceinline__ float sigm(float x) { return 1.0f / (1.0f + expf(-x)); }

// ---------------- init per call ----------------
__global__ __launch_bounds__(256) void init_state() {
  int i = blockIdx.x*256 + threadIdx.x;
  if (i < 3*NSEQ*EH) g_h[i] = 0.0f;
  if (i < 64) { g_cnt[i] = 0u; g_ep[i] = 0u; }
  if (i == 0) g_loss = 0.0f;
}

// ---------------- wih k-major for xproj ----------------
__global__ __launch_bounds__(256) void build_wt(
    const float* __restrict__ wih_t, const float* __restrict__ wih_d) {
  int idx = blockIdx.x*256 + threadIdx.x;
  if (idx >= 2*512*2048) return;
  int p = idx / (512*2048); int r2 = idx % (512*2048);
  int k = r2 / 2048; int r = r2 % 2048;
  const float* wih = p ? wih_d : wih_t;
  g_wT[p*512*2048 + k*2048 + r] = wih[r*512 + k];
}

// ---------------- recurrence weights: [path][cg][k][col512] ----------------
// cg<4: col c -> gate g=c>>7, j = cg*128 + (c&127), row r = g*512+j, val = whh[r][k]
// cg=4: col c -> attn col c, val = aw[c][k]
__global__ __launch_bounds__(256) void build_wt2(
    const float* __restrict__ whh_t, const float* __restrict__ whh_d,
    const float* __restrict__ aw_t,  const float* __restrict__ aw_d) {
  int idx = blockIdx.x*256 + threadIdx.x;
  if (idx >= 2*5*512*512) return;
  int p  = idx / (5*512*512); int rem = idx % (5*512*512);
  int cg = rem / (512*512);   int r2  = rem % (512*512);
  int k  = r2 >> 9;           int c   = r2 & 511;
  float v;
  if (cg < 4) {
    int r = (c >> 7)*512 + cg*128 + (c & 127);
    const float* whh = p ? whh_d : whh_t;
    v = whh[r*512 + k];
  } else {
    const float* aw = p ? aw_d : aw_t;
    v = aw[c*512 + k];
  }
  g_w2T[((size_t)(p*5 + cg)*512 + k)*512 + c] = v;
}

// ---------------- pre-gather embeddings ----------------
__global__ __launch_bounds__(128) void pregather(
    const int* __restrict__ tran, const int* __restrict__ da_tok,
    const int* __restrict__ dn_tok, const float* __restrict__ emb) {
  int row = blockIdx.x;
  int tok;
  if (row < XR_TRAN) tok = tran[row];
  else {
    int q = row - XR_TRAN;
    tok = (q < 32*TDOC) ? da_tok[q] : dn_tok[q - 32*TDOC];
  }
  const float4* src = (const float4*)&emb[(size_t)tok*EH];
  float4* dst = (float4*)&g_x[(size_t)row*EH];
  dst[threadIdx.x] = src[threadIdx.x];
}

// ---------------- hoisted xproj GEMM -> gate-interleaved layout ----------------
__global__ __launch_bounds__(256) void xproj_gemm(
    const float* __restrict__ b_t, const float* __restrict__ b_d) {
  __shared__ float As[2][16][128];
  __shared__ float Bs[2][16][128];
  const int mt = blockIdx.x >> 4, ntb = blockIdx.x & 15;
  const size_t mb = (size_t)mt * 128; const int nb = ntb * 128;
  const bool tp = (mb < XR_TRAN);
  const float* __restrict__ wT = g_wT + (tp ? 0 : 512*2048);
  const float* __restrict__ bias = tp ? b_t : b_d;
  const int tid = threadIdx.x, tx = tid & 15, ty = tid >> 4;
  float acc[8][8];
  #pragma unroll
  for (int i = 0; i < 8; ++i)
    #pragma unroll
    for (int j = 0; j < 8; ++j) acc[i][j] = 0.0f;

  auto stage = [&](int ks, int buf) {
    const int k0 = ks * 16;
    #pragma unroll
    for (int i = 0; i < 2; ++i) {
      int idx = i*256 + tid; int m = idx & 127, kc = idx >> 7;
      float4 v = *(const float4*)&g_x[(mb + m)*512 + k0 + kc*4];
      As[buf][kc*4+0][m] = v.x; As[buf][kc*4+1][m] = v.y;
      As[buf][kc*4+2][m] = v.z; As[buf][kc*4+3][m] = v.w;
    }
    #pragma unroll
    for (int i = 0; i < 2; ++i) {
      int idx = i*256 + tid; int n4 = idx & 31, kk = idx >> 5;
      *(float4*)&Bs[buf][kk][n4*4] = *(const float4*)&wT[(size_t)(k0+kk)*2048 + nb + n4*4];
    }
  };
  stage(0, 0); __syncthreads();
  for (int ks = 0; ks < 32; ++ks) {
    const int buf = ks & 1;
    if (ks < 31) stage(ks + 1, buf ^ 1);
    #pragma unroll
    for (int kk = 0; kk < 16; ++kk) {
      float a[8], b[8];
      *(float4*)&a[0] = *(const float4*)&As[buf][kk][ty*8];
      *(float4*)&a[4] = *(const float4*)&As[buf][kk][ty*8+4];
      *(float4*)&b[0] = *(const float4*)&Bs[buf][kk][tx*8];
      *(float4*)&b[4] = *(const float4*)&Bs[buf][kk][tx*8+4];
      #pragma unroll
      for (int i = 0; i < 8; ++i)
        #pragma unroll
        for (int j = 0; j < 8; ++j) acc[i][j] = fmaf(a[i], b[j], acc[i][j]);
    }
    __syncthreads();
  }
  // remap natural col (nb+cc) -> cg*512 + g*128 + cc'
  const int gg = nb >> 9, cgt = (nb & 511) >> 7;
  const int base2 = cgt*512 + gg*128;
  float b8[8];
  #pragma unroll
  for (int j = 0; j < 8; ++j) b8[j] = bias[nb + tx*8 + j];
  #pragma unroll
  for (int i = 0; i < 8; ++i) {
    float* dst = &g_xp[(mb + ty*8 + i)*2048 + base2 + tx*8];
    float4 o0 = make_float4(acc[i][0]+b8[0], acc[i][1]+b8[1], acc[i][2]+b8[2], acc[i][3]+b8[3]);
    float4 o1 = make_float4(acc[i][4]+b8[4], acc[i][5]+b8[5], acc[i][6]+b8[6], acc[i][7]+b8[7]);
    *(float4*)dst = o0; *(float4*)(dst+4) = o1;
  }
}

// ---------------- channel barrier (device-scope, deadlock-safe: 1 block/CU by LDS) ----
__device__ __forceinline__ void chan_barrier(int ch, unsigned nblk, unsigned ep1) {
  __syncthreads();
  if (threadIdx.x == 0) {
    __threadfence();                       // release: drain + make our writes visible
    unsigned old = atomicAdd(&g_cnt[ch*32], 1u);
    if (old == nblk - 1u) {
      __hip_atomic_store(&g_cnt[ch*32], 0u, __ATOMIC_RELAXED, __HIP_MEMORY_SCOPE_AGENT);
      __hip_atomic_store(&g_ep[ch*32], ep1, __ATOMIC_RELEASE, __HIP_MEMORY_SCOPE_AGENT);
    } else {
      while (__hip_atomic_load(&g_ep[ch*32], __ATOMIC_RELAXED, __HIP_MEMORY_SCOPE_AGENT) < ep1)
        __builtin_amdgcn_s_sleep(2);
    }
    __threadfence();                       // acquire: invalidate L1/L2 for fresh reads
  }
  __syncthreads();
}

// ---------------- recurrence GEMM per wave: 8 cols x SW seqs x 128 k ----------------
template<int SW>
__device__ __forceinline__ void gemm_block(const float* __restrict__ wsl,
                                           const float* __restrict__ ht,
                                           float* __restrict__ part,
                                           int kq, int sh, int lane) {
  float acc[8][SW];
  #pragma unroll
  for (int c = 0; c < 8; ++c)
    #pragma unroll
    for (int s = 0; s < SW; ++s) acc[c][s] = 0.0f;
  const float* hr[SW];
  #pragma unroll
  for (int s = 0; s < SW; ++s) hr[s] = ht + (sh*SW + s)*516 + kq*128;
  const float* wp = wsl + (size_t)kq*128*512 + 4*lane;
  #pragma unroll 2
  for (int k4 = 0; k4 < 32; ++k4) {
    float4 hv[SW];
    #pragma unroll
    for (int s = 0; s < SW; ++s) hv[s] = *(const float4*)&hr[s][k4*4];
    #pragma unroll
    for (int i4 = 0; i4 < 4; ++i4) {
      float4 w0 = *(const float4*)&wp[(size_t)(k4*4 + i4)*512];
      float4 w1 = *(const float4*)&wp[(size_t)(k4*4 + i4)*512 + 256];
      #pragma unroll
      for (int s = 0; s < SW; ++s) {
        const float* hvp = reinterpret_cast<const float*>(&hv[s]);
        float h = hvp[i4];
        acc[0][s] = fmaf(w0.x, h, acc[0][s]);
        acc[1][s] = fmaf(w0.y, h, acc[1][s]);
        acc[2][s] = fmaf(w0.z, h, acc[2][s]);
        acc[3][s] = fmaf(w0.w, h, acc[3][s]);
        acc[4][s] = fmaf(w1.x, h, acc[4][s]);
        acc[5][s] = fmaf(w1.y, h, acc[5][s]);
        acc[6][s] = fmaf(w1.z, h, acc[6][s]);
        acc[7][s] = fmaf(w1.w, h, acc[7][s]);
      }
    }
  }
  #pragma unroll
  for (int i = 0; i < 4; ++i) {
    float* p0 = &part[(size_t)(kq*512 + 4*lane + i)*9 + sh*SW];
    float* p1 = &part[(size_t)(kq*512 + 256 + 4*lane + i)*9 + sh*SW];
    #pragma unroll
    for (int s = 0; s < SW; ++s) { p0[s] = acc[i][s]; p1[s] = acc[4+i][s]; }
  }
}

// ---------------- persistent recurrence kernel ----------------
// 256 blocks x 512 thr; b%8 = XCD. x<5: tran cg=x, nt=b/8 (S=8, 160 blocks, ch0, 130 steps)
// x in 5..7: doc slot=(x-5)*32+b/8; slot<80: cg=slot/16, nt=slot%16 (S=4, ch1, 258 steps)
// LDS 105.5KB => exactly 1 block/CU => all 240 live blocks co-resident => barriers safe.
__global__ __launch_bounds__(512, 2) void persist(
    const int* __restrict__ tbl, const int* __restrict__ dal, const int* __restrict__ dnl,
    const float* __restrict__ ab_t, const float* __restrict__ ab_d,
    const float* __restrict__ sw_t, const float* __restrict__ sw_d,
    const float* __restrict__ sb_t, const float* __restrict__ sb_d) {
  __shared__ float sm[27008];   // 105.5 KB
  float* part = sm;             // [4][512][9] = 18432
  float* ht   = sm + 18432;     // [8][516]    = 4128
  float* cb   = sm + 22560;     // gate: c[8][128] | attn: acc[8][512] = 4096
  float* scr  = sm + 26656;     // [2][8] score ring
  float* ml   = sm + 26672;     // [8][2] {m,l}
  float* lenb = sm + 26688;     // [8]
  float* alb  = sm + 26696;     // [8][2] {alpha,e}

  const int b = blockIdx.x, tid = threadIdx.x;
  const int x = b & 7, m = b >> 3;
  bool tran; int cg, nt;
  if (x < 5) { tran = true; cg = x; nt = m; }
  else {
    int slot = (x - 5)*32 + m;
    if (slot >= 80) return;                  // 16 idle blocks
    tran = false; cg = slot / 16; nt = slot % 16;
  }
  const int ch    = tran ? 0 : 1;
  const int S     = tran ? 8 : 4;
  const int Ts    = tran ? TT : TDOC;
  const int Tmax  = tran ? (TT + 1) : (TDOC + 1);
  const unsigned nblk = tran ? 160u : 80u;
  const int sbase = tran ? nt*8 : NTRAN + nt*4;
  const bool isattn = (cg == 4);
  const float* __restrict__ wsl = g_w2T + (size_t)((tran ? 0 : 5) + cg)*512*512;
  const float* __restrict__ ab  = tran ? ab_t : ab_d;
  const float* __restrict__ sw  = tran ? sw_t : sw_d;
  const float  sb = tran ? sb_t[0] : sb_d[0];

  // init LDS state
  for (int i = tid; i < 4096; i += 512) cb[i] = 0.0f;
  if (tid < S) {
    ml[tid*2] = -3.0e38f; ml[tid*2+1] = 0.0f;
    int s = sbase + tid;
    int len = tran ? tbl[s] : (s < NTRAN+32 ? dal[s-NTRAN] : dnl[s-NTRAN-32]);
    lenb[tid] = (float)len;
  }
  __syncthreads();

  const int lane = tid & 63, w = tid >> 6;
  const int kq = w >> 1, sh = w & 1;

  for (int t = 0; t <= Tmax; ++t) {
    const int hp = (t + 2) % 3, hc = t % 3, h2 = (t + 1) % 3;
    const bool doGemm = isattn ? (t >= 1 && t <= Ts) : (t < Ts);

    // stage h_{t-1}
    if (doGemm) {
      for (int i = tid; i < S*64; i += 512) {
        int s = i >> 6, kk8 = (i & 63)*8;
        const float* src = &g_h[((size_t)hp*NSEQ + sbase + s)*EH + kk8];
        *(float4*)&ht[s*516 + kk8]     = *(const float4*)src;
        *(float4*)&ht[s*516 + kk8 + 4] = *(const float4*)(src + 4);
      }
    }
    // attn: per-seq online-softmax scalars for t-2 (owner thread), uses scr written at t-1
    if (isattn && t >= 2 && tid < S) {
      int s = tid;
      if ((float)(t - 2) < lenb[s]) {
        float sv = scr[(t & 1)*8 + s];
        float mo = ml[s*2], lo = ml[s*2+1];
        float mn = fmaxf(mo, sv);
        float a = expf(mo - mn), e = expf(sv - mn);
        alb[s*2] = a; alb[s*2+1] = e;
        ml[s*2] = mn; ml[s*2+1] = lo*a + e;
      } else { alb[s*2] = 1.0f; alb[s*2+1] = 0.0f; }
    }
    __syncthreads();

    // GEMM partials
    if (doGemm) {
      if (tran) gemm_block<4>(wsl, ht, part, kq, sh, lane);
      else      gemm_block<2>(wsl, ht, part, kq, sh, lane);
    }
    // attn Phase B: acc update with h_{t-2}
    if (isattn && t >= 2) {
      for (int i = tid; i < S*512; i += 512) {
        int s = i >> 9, d = i & 511;
        float a = alb[s*2], e = alb[s*2+1];
        if (!(a == 1.0f && e == 0.0f)) {
          float hv = g_h[((size_t)h2*NSEQ + sbase + s)*EH + d];
          cb[s*512 + d] = cb[s*512 + d]*a + e*hv;
        }
      }
    }
    __syncthreads();

    if (!isattn && t < Ts) {
      // gate finish: reduce kq partials + xp, pointwise c/h
      for (int i = tid; i < 128*S; i += 512) {
        int jl = i & 127, s = i >> 7;
        size_t row = tran ? (size_t)(sbase + s)*TT + t
                          : (size_t)XR_TRAN + (size_t)(sbase + s - NTRAN)*TDOC + t;
        const float* xr = &g_xp[row*2048 + cg*512];
        float u[4];
        #pragma unroll
        for (int g4 = 0; g4 < 4; ++g4) {
          float v = xr[g4*128 + jl];
          #pragma unroll
          for (int q = 0; q < 4; ++q) v += part[(size_t)(q*512 + g4*128 + jl)*9 + s];
          u[g4] = v;
        }
        float cv = cb[s*128 + jl];
        float cn = sigm(u[1])*cv + sigm(u[0])*tanhf(u[2]);
        float hn = sigm(u[3])*tanhf(cn);
        cb[s*128 + jl] = cn;
        g_h[((size_t)hc*NSEQ + sbase + s)*EH + cg*128 + jl] = hn;
      }
    }
    if (isattn && t >= 1 && (t - 1) < Ts) {
      // p = tanh(u+ab)*sw, then per-seq sum -> score(t-1)
      for (int i = tid; i < 512*S; i += 512) {
        int c = i & 511, s = i >> 9;
        float u = ab[c];
        #pragma unroll
        for (int q = 0; q < 4; ++q) u += part[(size_t)(q*512 + c)*9 + s];
        float p = tanhf(u) * sw[c];
        part[(size_t)c*9 + s] = p;         // own (c,s) slot: safe in-place
      }
      __syncthreads();
      if (w < S) {
        int s = w;
        float p = 0.0f;
        #pragma unroll
        for (int j = 0; j < 8; ++j) p += part[(size_t)(j*64 + lane)*9 + s];
        #pragma unroll
        for (int off = 32; off >= 1; off >>= 1) p += __shfl_xor(p, off, 64);
        if (lane == 0) scr[((t - 1) & 1)*8 + s] = p + sb;
      }
    }
    chan_barrier(ch, nblk, (unsigned)(t + 1));
  }

  // epilogue: attn blocks write pooled
  if (isattn) {
    for (int i = tid; i < S*512; i += 512) {
      int s = i >> 9, d = i & 511;
      float v = cb[s*512 + d] / ml[s*2+1];
      if (tran) v = tanhf(v);
      g_pool[(size_t)(sbase + s)*EH + d] = v;
    }
  }
}

// ---------------- per-batch cosine terms + loss ----------------
__global__ __launch_bounds__(256) void loss_partial() {
  __shared__ float red[5][4];
  int b = blockIdx.x, tid = threadIdx.x;
  float p[5] = {0.f, 0.f, 0.f, 0.f, 0.f};
  for (int j = tid; j < EH; j += 256) {
    float mx = -3.0e38f;
    #pragma unroll
    for (int bl = 0; bl < 8; bl++) mx = fmaxf(mx, g_pool[(b*8 + bl)*EH + j]);
    float da = g_pool[(NTRAN + b)*EH + j];
    float dn = g_pool[(NTRAN + 32 + b)*EH + j];
    p[0] += mx*mx; p[1] += da*da; p[2] += dn*dn; p[3] += mx*da; p[4] += mx*dn;
  }
  int lane = tid & 63, w = tid >> 6;
  #pragma unroll
  for (int i = 0; i < 5; i++) {
    float v = p[i];
    for (int off = 32; off >= 1; off >>= 1) v += __shfl_xor(v, off, 64);
    if (lane == 0) red[i][w] = v;
  }
  __syncthreads();
  if (tid == 0) {
    float cc = red[0][0]+red[0][1]+red[0][2]+red[0][3];
    float aa = red[1][0]+red[1][1]+red[1][2]+red[1][3];
    float nn = red[2][0]+red[2][1]+red[2][2]+red[2][3];
    float ca = red[3][0]+red[3][1]+red[3][2]+red[3][3];
    float cn = red[4][0]+red[4][1]+red[4][2]+red[4][3];
    float ncr = fmaxf(sqrtf(cc), 1e-8f);
    float nda = fmaxf(sqrtf(aa), 1e-8f);
    float ndn = fmaxf(sqrtf(nn), 1e-8f);
    float simA = ca / (ncr * nda);
    float simN = cn / (ncr * ndn);
    float term = fmaxf(0.05f - simA + simN, 1e-6f);
    atomicAdd(&g_loss, term * (1.0f / 32.0f));
  }
}

__global__ void write_out(float* __restrict__ out) {
  if (threadIdx.x == 0 && blockIdx.x == 0) out[0] = g_loss;
}

extern "C" void kernel_launch(void* const* d_in, const int* in_sizes, int n_in,
                              void* d_out, int out_size, void* d_ws, size_t ws_size,
                              hipStream_t stream) {
  (void)in_sizes; (void)n_in; (void)out_size; (void)d_ws; (void)ws_size;
  const int*   tran   = (const int*)d_in[0];
  const int*   tbl    = (const int*)d_in[2];
  const int*   da_tok = (const int*)d_in[3];
  const int*   dal    = (const int*)d_in[4];
  const int*   dn_tok = (const int*)d_in[5];
  const int*   dnl    = (const int*)d_in[6];
  const float* emb    = (const float*)d_in[7];
  const float* wih_t  = (const float*)d_in[8];
  const float* whh_t  = (const float*)d_in[9];
  const float* b_t    = (const float*)d_in[10];
  const float* wih_d  = (const float*)d_in[11];
  const float* whh_d  = (const float*)d_in[12];
  const float* b_d    = (const float*)d_in[13];
  const float* aw_t   = (const float*)d_in[14];
  const float* ab_t   = (const float*)d_in[15];
  const float* sw_t   = (const float*)d_in[16];
  const float* sb_t   = (const float*)d_in[17];
  const float* aw_d   = (const float*)d_in[18];
  const float* ab_d   = (const float*)d_in[19];
  const float* sw_d   = (const float*)d_in[20];
  const float* sb_d   = (const float*)d_in[21];

  init_state<<<(3*NSEQ*EH + 255)/256, 256, 0, stream>>>();
  build_wt<<<(2*512*2048 + 255)/256, 256, 0, stream>>>(wih_t, wih_d);
  build_wt2<<<(2*5*512*512 + 255)/256, 256, 0, stream>>>(whh_t, whh_d, aw_t, aw_d);
  pregather<<<XROWS, 128, 0, stream>>>(tran, da_tok, dn_tok, emb);
  xproj_gemm<<<(XROWS/128)*16, 256, 0, stream>>>(b_t, b_d);

  persist<<<256, 512, 0, stream>>>(tbl, dal, dnl,
      ab_t, ab_d, sw_t, sw_d, sb_t, sb_d);

  loss_partial<<<32, 256, 0, stream>>>();
  write_out<<<1, 64, 0, stream>>>((float*)d_out);
}

// Round 9
// 6996.603 us; speedup vs baseline: 4.5409x; 1.2926x over previous
//
#include <hip/hip_runtime.h>
#include <hip/hip_bf16.h>

#define NSEQ 320
#define NTRAN 256
#define TT 128
#define TDOC 256
#define EH 512
#define XR_TRAN (NTRAN*TT)            // 32768
#define XROWS (XR_TRAN + 64*TDOC)     // 49152

// ---- module-global scratch ----
__device__ float g_wT[2*512*2048];        // wih k-major [path][k][row] (xproj only)
__device__ __align__(16) unsigned short g_w2b[2*5*512*512]; // recurrence weights bf16 [path][cg][k][col]
__device__ float g_x [(size_t)XROWS*EH];  // gathered embeddings
__device__ float g_xp[(size_t)XROWS*2048];// hoisted xproj+bias, gate-interleaved cols
__device__ float g_h [3*NSEQ*EH];         // h ring [slot][seq][dim]
__device__ float g_pool[NSEQ*EH];
__device__ float g_loss;
__device__ unsigned g_cnt[64];
__device__ unsigned g_ep[64];

__device__ __forceinline__ float sigm(float x) { return 1.0f / (1.0f + expf(-x)); }

// ---------------- init per call ----------------
__global__ __launch_bounds__(256) void init_state() {
  int i = blockIdx.x*256 + threadIdx.x;
  if (i < 3*NSEQ*EH) g_h[i] = 0.0f;
  if (i < 64) { g_cnt[i] = 0u; g_ep[i] = 0u; }
  if (i == 0) g_loss = 0.0f;
}

// ---------------- wih k-major for xproj ----------------
__global__ __launch_bounds__(256) void build_wt(
    const float* __restrict__ wih_t, const float* __restrict__ wih_d) {
  int idx = blockIdx.x*256 + threadIdx.x;
  if (idx >= 2*512*2048) return;
  int p = idx / (512*2048); int r2 = idx % (512*2048);
  int k = r2 / 2048; int r = r2 % 2048;
  const float* wih = p ? wih_d : wih_t;
  g_wT[p*512*2048 + k*2048 + r] = wih[r*512 + k];
}

// ---------------- recurrence weights bf16: [path][cg][k][col512] ----------------
// cg<4: col c -> gate g=c>>7, j = cg*128 + (c&127), row r = g*512+j, val = whh[r][k]
// cg=4: col c -> attn col c, val = aw[c][k]
__global__ __launch_bounds__(256) void build_wt2(
    const float* __restrict__ whh_t, const float* __restrict__ whh_d,
    const float* __restrict__ aw_t,  const float* __restrict__ aw_d) {
  int idx = blockIdx.x*256 + threadIdx.x;
  if (idx >= 2*5*512*512) return;
  int p  = idx / (5*512*512); int rem = idx % (5*512*512);
  int cg = rem / (512*512);   int r2  = rem % (512*512);
  int k  = r2 >> 9;           int c   = r2 & 511;
  float v;
  if (cg < 4) {
    int r = (c >> 7)*512 + cg*128 + (c & 127);
    const float* whh = p ? whh_d : whh_t;
    v = whh[r*512 + k];
  } else {
    const float* aw = p ? aw_d : aw_t;
    v = aw[c*512 + k];
  }
  __hip_bfloat16 b = __float2bfloat16(v);
  g_w2b[((size_t)(p*5 + cg)*512 + k)*512 + c] = *reinterpret_cast<unsigned short*>(&b);
}

// ---------------- pre-gather embeddings ----------------
__global__ __launch_bounds__(128) void pregather(
    const int* __restrict__ tran, const int* __restrict__ da_tok,
    const int* __restrict__ dn_tok, const float* __restrict__ emb) {
  int row = blockIdx.x;
  int tok;
  if (row < XR_TRAN) tok = tran[row];
  else {
    int q = row - XR_TRAN;
    tok = (q < 32*TDOC) ? da_tok[q] : dn_tok[q - 32*TDOC];
  }
  const float4* src = (const float4*)&emb[(size_t)tok*EH];
  float4* dst = (float4*)&g_x[(size_t)row*EH];
  dst[threadIdx.x] = src[threadIdx.x];
}

// ---------------- hoisted xproj GEMM -> gate-interleaved layout ----------------
__global__ __launch_bounds__(256) void xproj_gemm(
    const float* __restrict__ b_t, const float* __restrict__ b_d) {
  __shared__ float As[2][16][128];
  __shared__ float Bs[2][16][128];
  const int mt = blockIdx.x >> 4, ntb = blockIdx.x & 15;
  const size_t mb = (size_t)mt * 128; const int nb = ntb * 128;
  const bool tp = (mb < XR_TRAN);
  const float* __restrict__ wT = g_wT + (tp ? 0 : 512*2048);
  const float* __restrict__ bias = tp ? b_t : b_d;
  const int tid = threadIdx.x, tx = tid & 15, ty = tid >> 4;
  float acc[8][8];
  #pragma unroll
  for (int i = 0; i < 8; ++i)
    #pragma unroll
    for (int j = 0; j < 8; ++j) acc[i][j] = 0.0f;

  auto stage = [&](int ks, int buf) {
    const int k0 = ks * 16;
    #pragma unroll
    for (int i = 0; i < 2; ++i) {
      int idx = i*256 + tid; int m = idx & 127, kc = idx >> 7;
      float4 v = *(const float4*)&g_x[(mb + m)*512 + k0 + kc*4];
      As[buf][kc*4+0][m] = v.x; As[buf][kc*4+1][m] = v.y;
      As[buf][kc*4+2][m] = v.z; As[buf][kc*4+3][m] = v.w;
    }
    #pragma unroll
    for (int i = 0; i < 2; ++i) {
      int idx = i*256 + tid; int n4 = idx & 31, kk = idx >> 5;
      *(float4*)&Bs[buf][kk][n4*4] = *(const float4*)&wT[(size_t)(k0+kk)*2048 + nb + n4*4];
    }
  };
  stage(0, 0); __syncthreads();
  for (int ks = 0; ks < 32; ++ks) {
    const int buf = ks & 1;
    if (ks < 31) stage(ks + 1, buf ^ 1);
    #pragma unroll
    for (int kk = 0; kk < 16; ++kk) {
      float a[8], b[8];
      *(float4*)&a[0] = *(const float4*)&As[buf][kk][ty*8];
      *(float4*)&a[4] = *(const float4*)&As[buf][kk][ty*8+4];
      *(float4*)&b[0] = *(const float4*)&Bs[buf][kk][tx*8];
      *(float4*)&b[4] = *(const float4*)&Bs[buf][kk][tx*8+4];
      #pragma unroll
      for (int i = 0; i < 8; ++i)
        #pragma unroll
        for (int j = 0; j < 8; ++j) acc[i][j] = fmaf(a[i], b[j], acc[i][j]);
    }
    __syncthreads();
  }
  const int gg = nb >> 9, cgt = (nb & 511) >> 7;
  const int base2 = cgt*512 + gg*128;
  float b8[8];
  #pragma unroll
  for (int j = 0; j < 8; ++j) b8[j] = bias[nb + tx*8 + j];
  #pragma unroll
  for (int i = 0; i < 8; ++i) {
    float* dst = &g_xp[(mb + ty*8 + i)*2048 + base2 + tx*8];
    float4 o0 = make_float4(acc[i][0]+b8[0], acc[i][1]+b8[1], acc[i][2]+b8[2], acc[i][3]+b8[3]);
    float4 o1 = make_float4(acc[i][4]+b8[4], acc[i][5]+b8[5], acc[i][6]+b8[6], acc[i][7]+b8[7]);
    *(float4*)dst = o0; *(float4*)(dst+4) = o1;
  }
}

// ---------------- channel barrier (device-scope; 1 block/CU by LDS) ----------------
__device__ __forceinline__ void chan_barrier(int ch, unsigned nblk, unsigned ep1) {
  __syncthreads();
  if (threadIdx.x == 0) {
    __threadfence();
    unsigned old = atomicAdd(&g_cnt[ch*32], 1u);
    if (old == nblk - 1u) {
      __hip_atomic_store(&g_cnt[ch*32], 0u, __ATOMIC_RELAXED, __HIP_MEMORY_SCOPE_AGENT);
      __hip_atomic_store(&g_ep[ch*32], ep1, __ATOMIC_RELEASE, __HIP_MEMORY_SCOPE_AGENT);
    } else {
      while (__hip_atomic_load(&g_ep[ch*32], __ATOMIC_RELAXED, __HIP_MEMORY_SCOPE_AGENT) < ep1)
        __builtin_amdgcn_s_sleep(2);
    }
    __threadfence();
  }
  __syncthreads();
}

// ---------------- recurrence GEMM: wave=kq(0..7, 64k), lane owns 8 contiguous cols ----
// bf16 weights (uint4 = 8 cols / load), fp32 h broadcast from LDS, fp32 accum.
// Two-round partial store keeps depth 4: kq<4 write part, sync, kq>=4 add.
template<int S>
__device__ __forceinline__ void gemm2(const unsigned short* __restrict__ wsl,
                                      const float* __restrict__ ht,
                                      float* __restrict__ part,
                                      int kq, int lane) {
  float acc[8][S];
  #pragma unroll
  for (int c = 0; c < 8; ++c)
    #pragma unroll
    for (int s = 0; s < S; ++s) acc[c][s] = 0.0f;
  const unsigned short* wp = wsl + (size_t)(kq*64)*512 + 8*lane;
  const float* hb = ht + kq*64;
  #pragma unroll 2
  for (int k4 = 0; k4 < 16; ++k4) {
    float4 hv[S];
    #pragma unroll
    for (int s = 0; s < S; ++s) hv[s] = *(const float4*)&hb[s*516 + k4*4];
    #pragma unroll
    for (int i4 = 0; i4 < 4; ++i4) {
      uint4 wv = *(const uint4*)(wp + (size_t)(k4*4 + i4)*512);
      float w0 = __uint_as_float(wv.x << 16);
      float w1 = __uint_as_float(wv.x & 0xFFFF0000u);
      float w2 = __uint_as_float(wv.y << 16);
      float w3 = __uint_as_float(wv.y & 0xFFFF0000u);
      float w4 = __uint_as_float(wv.z << 16);
      float w5 = __uint_as_float(wv.z & 0xFFFF0000u);
      float w6 = __uint_as_float(wv.w << 16);
      float w7 = __uint_as_float(wv.w & 0xFFFF0000u);
      #pragma unroll
      for (int s = 0; s < S; ++s) {
        float h = ((const float*)&hv[s])[i4];
        acc[0][s] = fmaf(w0, h, acc[0][s]);
        acc[1][s] = fmaf(w1, h, acc[1][s]);
        acc[2][s] = fmaf(w2, h, acc[2][s]);
        acc[3][s] = fmaf(w3, h, acc[3][s]);
        acc[4][s] = fmaf(w4, h, acc[4][s]);
        acc[5][s] = fmaf(w5, h, acc[5][s]);
        acc[6][s] = fmaf(w6, h, acc[6][s]);
        acc[7][s] = fmaf(w7, h, acc[7][s]);
      }
    }
  }
  if (kq < 4) {
    #pragma unroll
    for (int s = 0; s < S; ++s) {
      float* p = &part[(size_t)(kq*S + s)*516 + 8*lane];
      *(float4*)p     = make_float4(acc[0][s], acc[1][s], acc[2][s], acc[3][s]);
      *(float4*)(p+4) = make_float4(acc[4][s], acc[5][s], acc[6][s], acc[7][s]);
    }
  }
  __syncthreads();
  if (kq >= 4) {
    const int q = kq - 4;
    #pragma unroll
    for (int s = 0; s < S; ++s) {
      float* p = &part[(size_t)(q*S + s)*516 + 8*lane];
      float4 v0 = *(float4*)p, v1 = *(float4*)(p+4);
      v0.x += acc[0][s]; v0.y += acc[1][s]; v0.z += acc[2][s]; v0.w += acc[3][s];
      v1.x += acc[4][s]; v1.y += acc[5][s]; v1.z += acc[6][s]; v1.w += acc[7][s];
      *(float4*)p = v0; *(float4*)(p+4) = v1;
    }
  }
}

// ---------------- persistent recurrence kernel ----------------
// 256 blocks x 512 thr; b%8 = XCD. x<5: tran cg=x, nt=m (S=8, 160 blocks, ch0, 130 steps)
// x in 5..7: doc slot=(x-5)*32+m; slot<80: cg=slot/16, nt=slot%16 (S=4, ch1, 258 steps)
// LDS 99KB => 1 block/CU => all 240 live blocks co-resident => barriers safe.
__global__ __launch_bounds__(512, 2) void persist(
    const int* __restrict__ tbl, const int* __restrict__ dal, const int* __restrict__ dnl,
    const float* __restrict__ ab_t, const float* __restrict__ ab_d,
    const float* __restrict__ sw_t, const float* __restrict__ sw_d,
    const float* __restrict__ sb_t, const float* __restrict__ sb_d) {
  __shared__ float sm[24792];   // 99.2 KB
  float* part = sm;             // [4][S<=8][516] = 16512
  float* ht   = sm + 16512;     // [S<=8][516]    = 4128
  float* cb   = sm + 20640;     // gate c[S][128] | attn acc[S][512] = 4096
  float* scr  = sm + 24736;     // [2][8] score ring
  float* ml   = sm + 24752;     // [8][2] {m,l}
  float* lenb = sm + 24768;     // [8]
  float* alb  = sm + 24776;     // [8][2] {alpha,e}

  const int b = blockIdx.x, tid = threadIdx.x;
  const int x = b & 7, m = b >> 3;
  bool tran; int cg, nt;
  if (x < 5) { tran = true; cg = x; nt = m; }
  else {
    int slot = (x - 5)*32 + m;
    if (slot >= 80) return;
    tran = false; cg = slot / 16; nt = slot % 16;
  }
  const int ch    = tran ? 0 : 1;
  const int S     = tran ? 8 : 4;
  const int Ts    = tran ? TT : TDOC;
  const int Tmax  = tran ? (TT + 1) : (TDOC + 1);
  const unsigned nblk = tran ? 160u : 80u;
  const int sbase = tran ? nt*8 : NTRAN + nt*4;
  const bool isattn = (cg == 4);
  const unsigned short* __restrict__ wsl = g_w2b + (size_t)((tran ? 0 : 5) + cg)*512*512;
  const float* __restrict__ ab  = tran ? ab_t : ab_d;
  const float* __restrict__ sw  = tran ? sw_t : sw_d;
  const float  sb = tran ? sb_t[0] : sb_d[0];

  for (int i = tid; i < 4096; i += 512) cb[i] = 0.0f;
  if (tid < S) {
    ml[tid*2] = -3.0e38f; ml[tid*2+1] = 0.0f;
    int s = sbase + tid;
    int len = tran ? tbl[s] : (s < NTRAN+32 ? dal[s-NTRAN] : dnl[s-NTRAN-32]);
    lenb[tid] = (float)len;
  }
  __syncthreads();

  const int lane = tid & 63, w = tid >> 6;
  const int kq = w;

  for (int t = 0; t <= Tmax; ++t) {
    const int hp = (t + 2) % 3, hc = t % 3, h2 = (t + 1) % 3;
    const bool doGemm = isattn ? (t >= 1 && t <= Ts) : (t < Ts);

    // stage h_{t-1}
    if (doGemm) {
      for (int i = tid; i < S*64; i += 512) {
        int s = i >> 6, kk8 = (i & 63)*8;
        const float* src = &g_h[((size_t)hp*NSEQ + sbase + s)*EH + kk8];
        *(float4*)&ht[s*516 + kk8]     = *(const float4*)src;
        *(float4*)&ht[s*516 + kk8 + 4] = *(const float4*)(src + 4);
      }
    }
    if (isattn && t >= 2 && tid < S) {
      int s = tid;
      if ((float)(t - 2) < lenb[s]) {
        float sv = scr[(t & 1)*8 + s];
        float mo = ml[s*2], lo = ml[s*2+1];
        float mn = fmaxf(mo, sv);
        float a = expf(mo - mn), e = expf(sv - mn);
        alb[s*2] = a; alb[s*2+1] = e;
        ml[s*2] = mn; ml[s*2+1] = lo*a + e;
      } else { alb[s*2] = 1.0f; alb[s*2+1] = 0.0f; }
    }
    __syncthreads();

    // GEMM partials (two-round store inside; block-uniform call)
    if (doGemm) {
      if (tran) gemm2<8>(wsl, ht, part, kq, lane);
      else      gemm2<4>(wsl, ht, part, kq, lane);
    }
    // attn Phase B: acc update with h_{t-2}
    if (isattn && t >= 2) {
      for (int i = tid; i < S*512; i += 512) {
        int s = i >> 9, d = i & 511;
        float a = alb[s*2], e = alb[s*2+1];
        if (!(a == 1.0f && e == 0.0f)) {
          float hv = g_h[((size_t)h2*NSEQ + sbase + s)*EH + d];
          cb[s*512 + d] = cb[s*512 + d]*a + e*hv;
        }
      }
    }
    __syncthreads();

    if (!isattn && t < Ts) {
      for (int i = tid; i < 128*S; i += 512) {
        int jl = i & 127, s = i >> 7;
        size_t row = tran ? (size_t)(sbase + s)*TT + t
                          : (size_t)XR_TRAN + (size_t)(sbase + s - NTRAN)*TDOC + t;
        const float* xr = &g_xp[row*2048 + cg*512];
        float u[4];
        #pragma unroll
        for (int g4 = 0; g4 < 4; ++g4) {
          float v = xr[g4*128 + jl];
          #pragma unroll
          for (int q = 0; q < 4; ++q) v += part[(size_t)(q*S + s)*516 + g4*128 + jl];
          u[g4] = v;
        }
        float cv = cb[s*128 + jl];
        float cn = sigm(u[1])*cv + sigm(u[0])*tanhf(u[2]);
        float hn = sigm(u[3])*tanhf(cn);
        cb[s*128 + jl] = cn;
        g_h[((size_t)hc*NSEQ + sbase + s)*EH + cg*128 + jl] = hn;
      }
    }
    if (isattn && t >= 1 && (t - 1) < Ts) {
      for (int i = tid; i < 512*S; i += 512) {
        int c = i & 511, s = i >> 9;
        float u = ab[c];
        #pragma unroll
        for (int q = 0; q < 4; ++q) u += part[(size_t)(q*S + s)*516 + c];
        float p = tanhf(u) * sw[c];
        part[(size_t)s*516 + c] = p;      // own (c,s) slot: safe in-place
      }
      __syncthreads();
      if (w < S) {
        int s = w;
        float p = 0.0f;
        #pragma unroll
        for (int j = 0; j < 8; ++j) p += part[(size_t)s*516 + j*64 + lane];
        #pragma unroll
        for (int off = 32; off >= 1; off >>= 1) p += __shfl_xor(p, off, 64);
        if (lane == 0) scr[((t - 1) & 1)*8 + s] = p + sb;
      }
    }
    chan_barrier(ch, nblk, (unsigned)(t + 1));
  }

  if (isattn) {
    for (int i = tid; i < S*512; i += 512) {
      int s = i >> 9, d = i & 511;
      float v = cb[s*512 + d] / ml[s*2+1];
      if (tran) v = tanhf(v);
      g_pool[(size_t)(sbase + s)*EH + d] = v;
    }
  }
}

// ---------------- per-batch cosine terms + loss ----------------
__global__ __launch_bounds__(256) void loss_partial() {
  __shared__ float red[5][4];
  int b = blockIdx.x, tid = threadIdx.x;
  float p[5] = {0.f, 0.f, 0.f, 0.f, 0.f};
  for (int j = tid; j < EH; j += 256) {
    float mx = -3.0e38f;
    #pragma unroll
    for (int bl = 0; bl < 8; bl++) mx = fmaxf(mx, g_pool[(b*8 + bl)*EH + j]);
    float da = g_pool[(NTRAN + b)*EH + j];
    float dn = g_pool[(NTRAN + 32 + b)*EH + j];
    p[0] += mx*mx; p[1] += da*da; p[2] += dn*dn; p[3] += mx*da; p[4] += mx*dn;
  }
  int lane = tid & 63, w = tid >> 6;
  #pragma unroll
  for (int i = 0; i < 5; i++) {
    float v = p[i];
    for (int off = 32; off >= 1; off >>= 1) v += __shfl_xor(v, off, 64);
    if (lane == 0) red[i][w] = v;
  }
  __syncthreads();
  if (tid == 0) {
    float cc = red[0][0]+red[0][1]+red[0][2]+red[0][3];
    float aa = red[1][0]+red[1][1]+red[1][2]+red[1][3];
    float nn = red[2][0]+red[2][1]+red[2][2]+red[2][3];
    float ca = red[3][0]+red[3][1]+red[3][2]+red[3][3];
    float cn = red[4][0]+red[4][1]+red[4][2]+red[4][3];
    float ncr = fmaxf(sqrtf(cc), 1e-8f);
    float nda = fmaxf(sqrtf(aa), 1e-8f);
    float ndn = fmaxf(sqrtf(nn), 1e-8f);
    float simA = ca / (ncr * nda);
    float simN = cn / (ncr * ndn);
    float term = fmaxf(0.05f - simA + simN, 1e-6f);
    atomicAdd(&g_loss, term * (1.0f / 32.0f));
  }
}

__global__ void write_out(float* __restrict__ out) {
  if (threadIdx.x == 0 && blockIdx.x == 0) out[0] = g_loss;
}

extern "C" void kernel_launch(void* const* d_in, const int* in_sizes, int n_in,
                              void* d_out, int out_size, void* d_ws, size_t ws_size,
                              hipStream_t stream) {
  (void)in_sizes; (void)n_in; (void)out_size; (void)d_ws; (void)ws_size;
  const int*   tran   = (const int*)d_in[0];
  const int*   tbl    = (const int*)d_in[2];
  const int*   da_tok = (const int*)d_in[3];
  const int*   dal    = (const int*)d_in[4];
  const int*   dn_tok = (const int*)d_in[5];
  const int*   dnl    = (const int*)d_in[6];
  const float* emb    = (const float*)d_in[7];
  const float* wih_t  = (const float*)d_in[8];
  const float* whh_t  = (const float*)d_in[9];
  const float* b_t    = (const float*)d_in[10];
  const float* wih_d  = (const float*)d_in[11];
  const float* whh_d  = (const float*)d_in[12];
  const float* b_d    = (const float*)d_in[13];
  const float* aw_t   = (const float*)d_in[14];
  const float* ab_t   = (const float*)d_in[15];
  const float* sw_t   = (const float*)d_in[16];
  const float* sb_t   = (const float*)d_in[17];
  const float* aw_d   = (const float*)d_in[18];
  const float* ab_d   = (const float*)d_in[19];
  const float* sw_d   = (const float*)d_in[20];
  const float* sb_d   = (const float*)d_in[21];

  init_state<<<(3*NSEQ*EH + 255)/256, 256, 0, stream>>>();
  build_wt<<<(2*512*2048 + 255)/256, 256, 0, stream>>>(wih_t, wih_d);
  build_wt2<<<(2*5*512*512 + 255)/256, 256, 0, stream>>>(whh_t, whh_d, aw_t, aw_d);
  pregather<<<XROWS, 128, 0, stream>>>(tran, da_tok, dn_tok, emb);
  xproj_gemm<<<(XROWS/128)*16, 256, 0, stream>>>(b_t, b_d);

  persist<<<256, 512, 0, stream>>>(tbl, dal, dnl,
      ab_t, ab_d, sw_t, sw_d, sb_t, sb_d);

  loss_partial<<<32, 256, 0, stream>>>();
  write_out<<<1, 64, 0, stream>>>((float*)d_out);
}

// Round 10
// 4270.293 us; speedup vs baseline: 7.4399x; 1.6384x over previous
//
#include <hip/hip_runtime.h>
#include <hip/hip_bf16.h>

#define NSEQ 320
#define NTRAN 256
#define TT 128
#define TDOC 256
#define EH 512
#define XR_TRAN (NTRAN*TT)            // 32768
#define XROWS (XR_TRAN + 64*TDOC)     // 49152

// ---- module-global scratch ----
__device__ float g_wT[2*512*2048];        // wih k-major [path][k][row] (xproj only)
__device__ __align__(16) unsigned short g_w2b[2*5*512*512]; // recurrence weights bf16 [path][cg][k][col]
__device__ float g_x [(size_t)XROWS*EH];  // gathered embeddings
__device__ float g_xp[(size_t)XROWS*2048];// hoisted xproj+bias, gate-interleaved cols
__device__ float g_h [3*NSEQ*EH];         // h ring [slot][seq][dim] — system-scope accessed
__device__ float g_pool[NSEQ*EH];
__device__ float g_loss;
__device__ unsigned g_cnt[64];
__device__ unsigned g_ep[64];

__device__ __forceinline__ float sigm(float x) { return 1.0f / (1.0f + expf(-x)); }

// system-scope (sc0 sc1) scalar access: bypasses L1/L2 for THESE addresses only —
// no fence instructions, so weights/xp stay resident in L1/L2 across steps.
__device__ __forceinline__ float ldg_sys(const float* p) {
  return __hip_atomic_load(p, __ATOMIC_RELAXED, __HIP_MEMORY_SCOPE_SYSTEM);
}
__device__ __forceinline__ void stg_sys(float* p, float v) {
  __hip_atomic_store(p, v, __ATOMIC_RELAXED, __HIP_MEMORY_SCOPE_SYSTEM);
}

// ---------------- init per call ----------------
__global__ __launch_bounds__(256) void init_state() {
  int i = blockIdx.x*256 + threadIdx.x;
  if (i < 3*NSEQ*EH) g_h[i] = 0.0f;
  if (i < 64) { g_cnt[i] = 0u; g_ep[i] = 0u; }
  if (i == 0) g_loss = 0.0f;
}

// ---------------- wih k-major for xproj ----------------
__global__ __launch_bounds__(256) void build_wt(
    const float* __restrict__ wih_t, const float* __restrict__ wih_d) {
  int idx = blockIdx.x*256 + threadIdx.x;
  if (idx >= 2*512*2048) return;
  int p = idx / (512*2048); int r2 = idx % (512*2048);
  int k = r2 / 2048; int r = r2 % 2048;
  const float* wih = p ? wih_d : wih_t;
  g_wT[p*512*2048 + k*2048 + r] = wih[r*512 + k];
}

// ---------------- recurrence weights bf16: [path][cg][k][col512] ----------------
__global__ __launch_bounds__(256) void build_wt2(
    const float* __restrict__ whh_t, const float* __restrict__ whh_d,
    const float* __restrict__ aw_t,  const float* __restrict__ aw_d) {
  int idx = blockIdx.x*256 + threadIdx.x;
  if (idx >= 2*5*512*512) return;
  int p  = idx / (5*512*512); int rem = idx % (5*512*512);
  int cg = rem / (512*512);   int r2  = rem % (512*512);
  int k  = r2 >> 9;           int c   = r2 & 511;
  float v;
  if (cg < 4) {
    int r = (c >> 7)*512 + cg*128 + (c & 127);
    const float* whh = p ? whh_d : whh_t;
    v = whh[r*512 + k];
  } else {
    const float* aw = p ? aw_d : aw_t;
    v = aw[c*512 + k];
  }
  __hip_bfloat16 b = __float2bfloat16(v);
  g_w2b[((size_t)(p*5 + cg)*512 + k)*512 + c] = *reinterpret_cast<unsigned short*>(&b);
}

// ---------------- pre-gather embeddings ----------------
__global__ __launch_bounds__(128) void pregather(
    const int* __restrict__ tran, const int* __restrict__ da_tok,
    const int* __restrict__ dn_tok, const float* __restrict__ emb) {
  int row = blockIdx.x;
  int tok;
  if (row < XR_TRAN) tok = tran[row];
  else {
    int q = row - XR_TRAN;
    tok = (q < 32*TDOC) ? da_tok[q] : dn_tok[q - 32*TDOC];
  }
  const float4* src = (const float4*)&emb[(size_t)tok*EH];
  float4* dst = (float4*)&g_x[(size_t)row*EH];
  dst[threadIdx.x] = src[threadIdx.x];
}

// ---------------- hoisted xproj GEMM -> gate-interleaved layout ----------------
__global__ __launch_bounds__(256) void xproj_gemm(
    const float* __restrict__ b_t, const float* __restrict__ b_d) {
  __shared__ float As[2][16][128];
  __shared__ float Bs[2][16][128];
  const int mt = blockIdx.x >> 4, ntb = blockIdx.x & 15;
  const size_t mb = (size_t)mt * 128; const int nb = ntb * 128;
  const bool tp = (mb < XR_TRAN);
  const float* __restrict__ wT = g_wT + (tp ? 0 : 512*2048);
  const float* __restrict__ bias = tp ? b_t : b_d;
  const int tid = threadIdx.x, tx = tid & 15, ty = tid >> 4;
  float acc[8][8];
  #pragma unroll
  for (int i = 0; i < 8; ++i)
    #pragma unroll
    for (int j = 0; j < 8; ++j) acc[i][j] = 0.0f;

  auto stage = [&](int ks, int buf) {
    const int k0 = ks * 16;
    #pragma unroll
    for (int i = 0; i < 2; ++i) {
      int idx = i*256 + tid; int m = idx & 127, kc = idx >> 7;
      float4 v = *(const float4*)&g_x[(mb + m)*512 + k0 + kc*4];
      As[buf][kc*4+0][m] = v.x; As[buf][kc*4+1][m] = v.y;
      As[buf][kc*4+2][m] = v.z; As[buf][kc*4+3][m] = v.w;
    }
    #pragma unroll
    for (int i = 0; i < 2; ++i) {
      int idx = i*256 + tid; int n4 = idx & 31, kk = idx >> 5;
      *(float4*)&Bs[buf][kk][n4*4] = *(const float4*)&wT[(size_t)(k0+kk)*2048 + nb + n4*4];
    }
  };
  stage(0, 0); __syncthreads();
  for (int ks = 0; ks < 32; ++ks) {
    const int buf = ks & 1;
    if (ks < 31) stage(ks + 1, buf ^ 1);
    #pragma unroll
    for (int kk = 0; kk < 16; ++kk) {
      float a[8], b[8];
      *(float4*)&a[0] = *(const float4*)&As[buf][kk][ty*8];
      *(float4*)&a[4] = *(const float4*)&As[buf][kk][ty*8+4];
      *(float4*)&b[0] = *(const float4*)&Bs[buf][kk][tx*8];
      *(float4*)&b[4] = *(const float4*)&Bs[buf][kk][tx*8+4];
      #pragma unroll
      for (int i = 0; i < 8; ++i)
        #pragma unroll
        for (int j = 0; j < 8; ++j) acc[i][j] = fmaf(a[i], b[j], acc[i][j]);
    }
    __syncthreads();
  }
  const int gg = nb >> 9, cgt = (nb & 511) >> 7;
  const int base2 = cgt*512 + gg*128;
  float b8[8];
  #pragma unroll
  for (int j = 0; j < 8; ++j) b8[j] = bias[nb + tx*8 + j];
  #pragma unroll
  for (int i = 0; i < 8; ++i) {
    float* dst = &g_xp[(mb + ty*8 + i)*2048 + base2 + tx*8];
    float4 o0 = make_float4(acc[i][0]+b8[0], acc[i][1]+b8[1], acc[i][2]+b8[2], acc[i][3]+b8[3]);
    float4 o1 = make_float4(acc[i][4]+b8[4], acc[i][5]+b8[5], acc[i][6]+b8[6], acc[i][7]+b8[7]);
    *(float4*)dst = o0; *(float4*)(dst+4) = o1;
  }
}

// ---------------- cache-transparent channel barrier ----------------
// __syncthreads drains each wave's vmcnt(0) (compiler-guaranteed), so all this
// block's system-scope h stores are at the coherence point before we signal.
// Relaxed L3 atomics only — NO threadfence => NO L2 writeback/invalidate =>
// weights and xp stay L2-resident across steps (the R9 barrier flushed them).
__device__ __forceinline__ void chan_barrier(int ch, unsigned nblk, unsigned ep1) {
  __syncthreads();
  if (threadIdx.x == 0) {
    unsigned old = atomicAdd(&g_cnt[ch*32], 1u);
    if (old == nblk - 1u) {
      __hip_atomic_store(&g_cnt[ch*32], 0u, __ATOMIC_RELAXED, __HIP_MEMORY_SCOPE_AGENT);
      __hip_atomic_store(&g_ep[ch*32], ep1, __ATOMIC_RELAXED, __HIP_MEMORY_SCOPE_AGENT);
    } else {
      while (__hip_atomic_load(&g_ep[ch*32], __ATOMIC_RELAXED, __HIP_MEMORY_SCOPE_AGENT) < ep1)
        __builtin_amdgcn_s_sleep(2);
    }
  }
  __syncthreads();
}

// ---------------- recurrence GEMM: wave=kq(0..7, 64k), lane owns 8 contiguous cols ----
template<int S>
__device__ __forceinline__ void gemm2(const unsigned short* __restrict__ wsl,
                                      const float* __restrict__ ht,
                                      float* __restrict__ part,
                                      int kq, int lane) {
  float acc[8][S];
  #pragma unroll
  for (int c = 0; c < 8; ++c)
    #pragma unroll
    for (int s = 0; s < S; ++s) acc[c][s] = 0.0f;
  const unsigned short* wp = wsl + (size_t)(kq*64)*512 + 8*lane;
  const float* hb = ht + kq*64;
  #pragma unroll 2
  for (int k4 = 0; k4 < 16; ++k4) {
    float4 hv[S];
    #pragma unroll
    for (int s = 0; s < S; ++s) hv[s] = *(const float4*)&hb[s*516 + k4*4];
    #pragma unroll
    for (int i4 = 0; i4 < 4; ++i4) {
      uint4 wv = *(const uint4*)(wp + (size_t)(k4*4 + i4)*512);
      float w0 = __uint_as_float(wv.x << 16);
      float w1 = __uint_as_float(wv.x & 0xFFFF0000u);
      float w2 = __uint_as_float(wv.y << 16);
      float w3 = __uint_as_float(wv.y & 0xFFFF0000u);
      float w4 = __uint_as_float(wv.z << 16);
      float w5 = __uint_as_float(wv.z & 0xFFFF0000u);
      float w6 = __uint_as_float(wv.w << 16);
      float w7 = __uint_as_float(wv.w & 0xFFFF0000u);
      #pragma unroll
      for (int s = 0; s < S; ++s) {
        float h = ((const float*)&hv[s])[i4];
        acc[0][s] = fmaf(w0, h, acc[0][s]);
        acc[1][s] = fmaf(w1, h, acc[1][s]);
        acc[2][s] = fmaf(w2, h, acc[2][s]);
        acc[3][s] = fmaf(w3, h, acc[3][s]);
        acc[4][s] = fmaf(w4, h, acc[4][s]);
        acc[5][s] = fmaf(w5, h, acc[5][s]);
        acc[6][s] = fmaf(w6, h, acc[6][s]);
        acc[7][s] = fmaf(w7, h, acc[7][s]);
      }
    }
  }
  if (kq < 4) {
    #pragma unroll
    for (int s = 0; s < S; ++s) {
      float* p = &part[(size_t)(kq*S + s)*516 + 8*lane];
      *(float4*)p     = make_float4(acc[0][s], acc[1][s], acc[2][s], acc[3][s]);
      *(float4*)(p+4) = make_float4(acc[4][s], acc[5][s], acc[6][s], acc[7][s]);
    }
  }
  __syncthreads();
  if (kq >= 4) {
    const int q = kq - 4;
    #pragma unroll
    for (int s = 0; s < S; ++s) {
      float* p = &part[(size_t)(q*S + s)*516 + 8*lane];
      float4 v0 = *(float4*)p, v1 = *(float4*)(p+4);
      v0.x += acc[0][s]; v0.y += acc[1][s]; v0.z += acc[2][s]; v0.w += acc[3][s];
      v1.x += acc[4][s]; v1.y += acc[5][s]; v1.z += acc[6][s]; v1.w += acc[7][s];
      *(float4*)p = v0; *(float4*)(p+4) = v1;
    }
  }
}

// ---------------- persistent recurrence kernel ----------------
// 256 blocks x 512 thr; b%8 = XCD. x<5: tran cg=x, nt=m (S=8, 160 blocks, ch0, 130 steps)
// x in 5..7: doc slot=(x-5)*32+m; slot<80: cg=slot/16, nt=slot%16 (S=4, ch1, 258 steps)
// LDS 99KB => 1 block/CU => all 240 live blocks co-resident => barriers safe.
__global__ __launch_bounds__(512, 2) void persist(
    const int* __restrict__ tbl, const int* __restrict__ dal, const int* __restrict__ dnl,
    const float* __restrict__ ab_t, const float* __restrict__ ab_d,
    const float* __restrict__ sw_t, const float* __restrict__ sw_d,
    const float* __restrict__ sb_t, const float* __restrict__ sb_d) {
  __shared__ float sm[24792];   // 99.2 KB
  float* part = sm;             // [4][S<=8][516] = 16512
  float* ht   = sm + 16512;     // [S<=8][516]    = 4128
  float* cb   = sm + 20640;     // gate c[S][128] | attn acc[S][512] = 4096
  float* scr  = sm + 24736;     // [2][8] score ring
  float* ml   = sm + 24752;     // [8][2] {m,l}
  float* lenb = sm + 24768;     // [8]
  float* alb  = sm + 24776;     // [8][2] {alpha,e}

  const int b = blockIdx.x, tid = threadIdx.x;
  const int x = b & 7, m = b >> 3;
  bool tran; int cg, nt;
  if (x < 5) { tran = true; cg = x; nt = m; }
  else {
    int slot = (x - 5)*32 + m;
    if (slot >= 80) return;
    tran = false; cg = slot / 16; nt = slot % 16;
  }
  const int ch    = tran ? 0 : 1;
  const int S     = tran ? 8 : 4;
  const int Ts    = tran ? TT : TDOC;
  const int Tmax  = tran ? (TT + 1) : (TDOC + 1);
  const unsigned nblk = tran ? 160u : 80u;
  const int sbase = tran ? nt*8 : NTRAN + nt*4;
  const bool isattn = (cg == 4);
  const unsigned short* __restrict__ wsl = g_w2b + (size_t)((tran ? 0 : 5) + cg)*512*512;
  const float* __restrict__ ab  = tran ? ab_t : ab_d;
  const float* __restrict__ sw  = tran ? sw_t : sw_d;
  const float  sb = tran ? sb_t[0] : sb_d[0];

  for (int i = tid; i < 4096; i += 512) cb[i] = 0.0f;
  if (tid < S) {
    ml[tid*2] = -3.0e38f; ml[tid*2+1] = 0.0f;
    int s = sbase + tid;
    int len = tran ? tbl[s] : (s < NTRAN+32 ? dal[s-NTRAN] : dnl[s-NTRAN-32]);
    lenb[tid] = (float)len;
  }
  __syncthreads();

  const int lane = tid & 63, w = tid >> 6;
  const int kq = w;

  for (int t = 0; t <= Tmax; ++t) {
    const int hp = (t + 2) % 3, hc = t % 3, h2 = (t + 1) % 3;
    const bool doGemm = isattn ? (t >= 1 && t <= Ts) : (t < Ts);

    // stage h_{t-1} (system-scope scalar loads; coalesced; 8/4 per thread)
    if (doGemm) {
      const float* hsrc = &g_h[(size_t)hp*NSEQ*EH + (size_t)sbase*EH];
      for (int i = tid; i < S*512; i += 512) {
        int s = i >> 9, d = i & 511;
        ht[s*516 + d] = ldg_sys(hsrc + s*EH + d);
      }
    }
    if (isattn && t >= 2 && tid < S) {
      int s = tid;
      if ((float)(t - 2) < lenb[s]) {
        float sv = scr[(t & 1)*8 + s];
        float mo = ml[s*2], lo = ml[s*2+1];
        float mn = fmaxf(mo, sv);
        float a = expf(mo - mn), e = expf(sv - mn);
        alb[s*2] = a; alb[s*2+1] = e;
        ml[s*2] = mn; ml[s*2+1] = lo*a + e;
      } else { alb[s*2] = 1.0f; alb[s*2+1] = 0.0f; }
    }
    __syncthreads();

    // GEMM partials (two-round store inside; block-uniform call)
    if (doGemm) {
      if (tran) gemm2<8>(wsl, ht, part, kq, lane);
      else      gemm2<4>(wsl, ht, part, kq, lane);
    }
    // attn Phase B: acc update with h_{t-2}
    if (isattn && t >= 2) {
      for (int i = tid; i < S*512; i += 512) {
        int s = i >> 9, d = i & 511;
        float a = alb[s*2], e = alb[s*2+1];
        if (!(a == 1.0f && e == 0.0f)) {
          float hv = ldg_sys(&g_h[((size_t)h2*NSEQ + sbase + s)*EH + d]);
          cb[s*512 + d] = cb[s*512 + d]*a + e*hv;
        }
      }
    }
    __syncthreads();

    if (!isattn && t < Ts) {
      for (int i = tid; i < 128*S; i += 512) {
        int jl = i & 127, s = i >> 7;
        size_t row = tran ? (size_t)(sbase + s)*TT + t
                          : (size_t)XR_TRAN + (size_t)(sbase + s - NTRAN)*TDOC + t;
        const float* xr = &g_xp[row*2048 + cg*512];
        float u[4];
        #pragma unroll
        for (int g4 = 0; g4 < 4; ++g4) {
          float v = xr[g4*128 + jl];
          #pragma unroll
          for (int q = 0; q < 4; ++q) v += part[(size_t)(q*S + s)*516 + g4*128 + jl];
          u[g4] = v;
        }
        float cv = cb[s*128 + jl];
        float cn = sigm(u[1])*cv + sigm(u[0])*tanhf(u[2]);
        float hn = sigm(u[3])*tanhf(cn);
        cb[s*128 + jl] = cn;
        stg_sys(&g_h[((size_t)hc*NSEQ + sbase + s)*EH + cg*128 + jl], hn);
      }
    }
    if (isattn && t >= 1 && (t - 1) < Ts) {
      for (int i = tid; i < 512*S; i += 512) {
        int c = i & 511, s = i >> 9;
        float u = ab[c];
        #pragma unroll
        for (int q = 0; q < 4; ++q) u += part[(size_t)(q*S + s)*516 + c];
        float p = tanhf(u) * sw[c];
        part[(size_t)s*516 + c] = p;      // own (c,s) slot: safe in-place
      }
      __syncthreads();
      if (w < S) {
        int s = w;
        float p = 0.0f;
        #pragma unroll
        for (int j = 0; j < 8; ++j) p += part[(size_t)s*516 + j*64 + lane];
        #pragma unroll
        for (int off = 32; off >= 1; off >>= 1) p += __shfl_xor(p, off, 64);
        if (lane == 0) scr[((t - 1) & 1)*8 + s] = p + sb;
      }
    }
    chan_barrier(ch, nblk, (unsigned)(t + 1));
  }

  if (isattn) {
    for (int i = tid; i < S*512; i += 512) {
      int s = i >> 9, d = i & 511;
      float v = cb[s*512 + d] / ml[s*2+1];
      if (tran) v = tanhf(v);
      g_pool[(size_t)(sbase + s)*EH + d] = v;
    }
  }
}

// ---------------- per-batch cosine terms + loss ----------------
__global__ __launch_bounds__(256) void loss_partial() {
  __shared__ float red[5][4];
  int b = blockIdx.x, tid = threadIdx.x;
  float p[5] = {0.f, 0.f, 0.f, 0.f, 0.f};
  for (int j = tid; j < EH; j += 256) {
    float mx = -3.0e38f;
    #pragma unroll
    for (int bl = 0; bl < 8; bl++) mx = fmaxf(mx, g_pool[(b*8 + bl)*EH + j]);
    float da = g_pool[(NTRAN + b)*EH + j];
    float dn = g_pool[(NTRAN + 32 + b)*EH + j];
    p[0] += mx*mx; p[1] += da*da; p[2] += dn*dn; p[3] += mx*da; p[4] += mx*dn;
  }
  int lane = tid & 63, w = tid >> 6;
  #pragma unroll
  for (int i = 0; i < 5; i++) {
    float v = p[i];
    for (int off = 32; off >= 1; off >>= 1) v += __shfl_xor(v, off, 64);
    if (lane == 0) red[i][w] = v;
  }
  __syncthreads();
  if (tid == 0) {
    float cc = red[0][0]+red[0][1]+red[0][2]+red[0][3];
    float aa = red[1][0]+red[1][1]+red[1][2]+red[1][3];
    float nn = red[2][0]+red[2][1]+red[2][2]+red[2][3];
    float ca = red[3][0]+red[3][1]+red[3][2]+red[3][3];
    float cn = red[4][0]+red[4][1]+red[4][2]+red[4][3];
    float ncr = fmaxf(sqrtf(cc), 1e-8f);
    float nda = fmaxf(sqrtf(aa), 1e-8f);
    float ndn = fmaxf(sqrtf(nn), 1e-8f);
    float simA = ca / (ncr * nda);
    float simN = cn / (ncr * ndn);
    float term = fmaxf(0.05f - simA + simN, 1e-6f);
    atomicAdd(&g_loss, term * (1.0f / 32.0f));
  }
}

__global__ void write_out(float* __restrict__ out) {
  if (threadIdx.x == 0 && blockIdx.x == 0) out[0] = g_loss;
}

extern "C" void kernel_launch(void* const* d_in, const int* in_sizes, int n_in,
                              void* d_out, int out_size, void* d_ws, size_t ws_size,
                              hipStream_t stream) {
  (void)in_sizes; (void)n_in; (void)out_size; (void)d_ws; (void)ws_size;
  const int*   tran   = (const int*)d_in[0];
  const int*   tbl    = (const int*)d_in[2];
  const int*   da_tok = (const int*)d_in[3];
  const int*   dal    = (const int*)d_in[4];
  const int*   dn_tok = (const int*)d_in[5];
  const int*   dnl    = (const int*)d_in[6];
  const float* emb    = (const float*)d_in[7];
  const float* wih_t  = (const float*)d_in[8];
  const float* whh_t  = (const float*)d_in[9];
  const float* b_t    = (const float*)d_in[10];
  const float* wih_d  = (const float*)d_in[11];
  const float* whh_d  = (const float*)d_in[12];
  const float* b_d    = (const float*)d_in[13];
  const float* aw_t   = (const float*)d_in[14];
  const float* ab_t   = (const float*)d_in[15];
  const float* sw_t   = (const float*)d_in[16];
  const float* sb_t   = (const float*)d_in[17];
  const float* aw_d   = (const float*)d_in[18];
  const float* ab_d   = (const float*)d_in[19];
  const float* sw_d   = (const float*)d_in[20];
  const float* sb_d   = (const float*)d_in[21];

  init_state<<<(3*NSEQ*EH + 255)/256, 256, 0, stream>>>();
  build_wt<<<(2*512*2048 + 255)/256, 256, 0, stream>>>(wih_t, wih_d);
  build_wt2<<<(2*5*512*512 + 255)/256, 256, 0, stream>>>(whh_t, whh_d, aw_t, aw_d);
  pregather<<<XROWS, 128, 0, stream>>>(tran, da_tok, dn_tok, emb);
  xproj_gemm<<<(XROWS/128)*16, 256, 0, stream>>>(b_t, b_d);

  persist<<<256, 512, 0, stream>>>(tbl, dal, dnl,
      ab_t, ab_d, sw_t, sw_d, sb_t, sb_d);

  loss_partial<<<32, 256, 0, stream>>>();
  write_out<<<1, 64, 0, stream>>>((float*)d_out);
}